// Round 6
// baseline (1232.433 us; speedup 1.0000x reference)
//
#include <hip/hip_runtime.h>
#include <hip/hip_bf16.h>
#include <math.h>

// ---------------------------------------------------------------------------
// VQ-VAE forward. B=4096, G=20000, dims 2048/1024/512, K=8192 codes.
// Round 6: gemm256 with register fragment-prefetch — every cluster's LDS
// reads issue one cluster ahead (A-frags double-buffered aP/aQ, B-frags b0/b1
// persist), next-tile phase-A reads issue at tile tail behind counted
// vmcnt(8). 3 barriers/tile, never vmcnt(0) in main loop. VQ score GEMM now
// also on gemm256 with fused 256-row argmin epilogue.
// ---------------------------------------------------------------------------

typedef short v8s __attribute__((ext_vector_type(8)));
typedef float v4f __attribute__((ext_vector_type(4)));
typedef unsigned short u16;
typedef unsigned long long u64;

typedef const unsigned int __attribute__((address_space(1)))* as1p;
typedef unsigned int __attribute__((address_space(3)))* as3p;

__device__ __forceinline__ void gload_lds16(const void* g, void* l) {
    __builtin_amdgcn_global_load_lds((as1p)g, (as3p)l, 16, 0, 0);
}

__device__ __forceinline__ u16 f2b(float f) {
    return __builtin_bit_cast(u16, __float2bfloat16(f));
}

__device__ __forceinline__ unsigned int float_orderable(float f)
{
    unsigned int b = __float_as_uint(f);
    return (b & 0x80000000u) ? ~b : (b | 0x80000000u);
}

#define FENCE asm volatile("" ::: "memory")

// ---------------------------------------------------------------------------
// 256x256 tile, 512 threads (8 waves = 2Mx4N), BK=64, double-buffered LDS
// (dynamic 128 KB), 4 MFMA clusters/K-tile with one-cluster-ahead register
// fragment prefetch, LDS slot-XOR swizzle (conflict-free, round-4-verified).
// EPI: 0 = +bias f32 store (col<N masked); 2 = fused per-row argmin
// (score = bias - 2*acc, u64 atomicMin, no C write); 3 = raw f32 partials,
// K split over blockIdx.z. K%64==0; M%256==0; >=3 K-tiles; nwg%8==0.
// ---------------------------------------------------------------------------
template<int EPI>
__global__ __launch_bounds__(512, 2) void gemm256(
    const u16* __restrict__ A, const u16* __restrict__ Bt,
    const float* __restrict__ bias, float* __restrict__ Cf,
    u64* __restrict__ packed, int M, int N, int K, int sA, int sB)
{
    extern __shared__ char lds[];   // [2][A 32K | B 32K] = 128 KB

    // bijective XCD swizzle (nwg % 8 == 0)
    const int gx = gridDim.x, gy = gridDim.y, gz = gridDim.z;
    const int nwg = gx * gy * gz;
    int flat = (blockIdx.z * gy + blockIdx.y) * gx + blockIdx.x;
    flat = (flat & 7) * (nwg >> 3) + (flat >> 3);
    const int bx = flat % gx;
    const int rem = flat / gx;
    const int by = rem % gy;
    const int bz = rem / gy;

    const int bm = by * 256;
    const int bn = bx * 256;

    const int tiles = K >> 6;
    int t0 = 0, t1 = tiles;
    if (EPI == 3) {
        const int qz = tiles / gz, rz = tiles % gz;
        t0 = bz * qz + (bz < rz ? bz : rz);
        t1 = t0 + qz + (bz < rz ? 1 : 0);
        Cf += (size_t)bz * ((size_t)M * N);
    }

    const int tid = threadIdx.x;
    const int wv = tid >> 6;
    const int ln = tid & 63;

    // staging: wave wv stages 1KB chunks; unit J covers rows [J*64, J*64+64).
    // LDS linear; global source column pre-swizzled: slot ^= (row&7).
    const int srow = wv * 8 + (ln >> 3);
    const int scol = (((ln & 7) ^ ((ln >> 3) & 7))) * 8;
    const u16* Asrc = A + (size_t)(bm + srow) * sA + scol;
    const u16* Bsrc = Bt + (size_t)(bn + srow) * sB + scol;
    char* stA = lds + wv * 1024;
    char* stB = lds + 32768 + wv * 1024;

#define STG_A(P, KT, J)                                                       \
    gload_lds16(Asrc + ((size_t)(KT) << 6) + (size_t)(J) * 64 * sA,           \
                stA + (P) * 65536 + (J) * 8192)
#define STG_B(P, KT, J)                                                       \
    gload_lds16(Bsrc + ((size_t)(KT) << 6) + (size_t)(J) * 64 * sB,           \
                stB + (P) * 65536 + (J) * 8192)
// mid-6: all B units + A units {0,2} (rows 0-63,128-191 = per-wave mh0 rows)
#define STAGE_MID(P, KT)                                                      \
    { STG_B(P, KT, 0); STG_B(P, KT, 1); STG_B(P, KT, 2); STG_B(P, KT, 3);     \
      STG_A(P, KT, 0); STG_A(P, KT, 2); }
// end-2: A units {1,3} (rows 64-127,192-255 = per-wave mh1 rows)
#define STAGE_END(P, KT)                                                      \
    { STG_A(P, KT, 1); STG_A(P, KT, 3); }

    // fragment read bases (swizzled: byte col ^= (row&7)<<4)
    const int wr = wv >> 2, wc = wv & 3;
    const int fr = ln & 15;
    const int q = ln >> 4;
    const int swz = (fr & 7) << 4;
    const char* Afrag = lds + (size_t)(wr * 128 + fr) * 128;
    const char* Bfrag = lds + 32768 + (size_t)(wc * 64 + fr) * 128;

    v4f acc[8][4];
    #pragma unroll
    for (int m = 0; m < 8; ++m)
        #pragma unroll
        for (int n = 0; n < 4; ++n) acc[m][n] = (v4f)(0.f);

    v8s aP[4], aQ[4], b0[4], b1[4];

#define LD_A(REG, PP, KH, MH)                                                 \
    {                                                                         \
        const char* Ab_ = Afrag + (PP) * 65536;                               \
        const int cb_ = ((KH) * 64 + q * 16) ^ swz;                           \
        _Pragma("unroll")                                                     \
        for (int m = 0; m < 4; ++m)                                           \
            REG[m] = *(const v8s*)(Ab_ + ((MH) * 4 + m) * 2048 + cb_);        \
    }
#define LD_B(REG, PP, KH)                                                     \
    {                                                                         \
        const char* Bb_ = Bfrag + (PP) * 65536;                               \
        const int cb_ = ((KH) * 64 + q * 16) ^ swz;                           \
        _Pragma("unroll")                                                     \
        for (int n = 0; n < 4; ++n)                                           \
            REG[n] = *(const v8s*)(Bb_ + n * 2048 + cb_);                     \
    }
#define MMA(AREG, BREG, MH)                                                   \
    {                                                                         \
        __builtin_amdgcn_s_setprio(1);                                        \
        _Pragma("unroll")                                                     \
        for (int m = 0; m < 4; ++m)                                           \
            _Pragma("unroll")                                                 \
            for (int n = 0; n < 4; ++n)                                       \
                acc[(MH) * 4 + m][n] =                                        \
                    __builtin_amdgcn_mfma_f32_16x16x32_bf16(                  \
                        AREG[m], BREG[n], acc[(MH) * 4 + m][n], 0, 0, 0);     \
        __builtin_amdgcn_s_setprio(0);                                        \
    }

    // prologue: stage two tiles; load tile-t0 phase-A frags (needs MID(t0))
    STAGE_MID(0, t0); STAGE_END(0, t0);
    STAGE_MID(1, t0 + 1); STAGE_END(1, t0 + 1);
    asm volatile("s_waitcnt vmcnt(10)" ::: "memory");   // retire MID(t0)
    FENCE; __builtin_amdgcn_s_barrier(); FENCE;
    LD_B(b0, 0, 0); LD_A(aP, 0, 0, 0);

    int cur = 0;
    for (int t = t0; t < t1 - 2; ++t) {
        // entry: retire {MID(t), END(t)} (issued >=1 full tile ago)
        asm volatile("s_waitcnt vmcnt(8)" ::: "memory");
        FENCE; __builtin_amdgcn_s_barrier(); FENCE;
        LD_B(b1, cur, 1); LD_A(aQ, cur, 1, 0);   // phase-B frags
        MMA(aP, b0, 0);                           // cluster A (kh0 mh0)
        LD_A(aP, cur, 0, 1);                      // phase-C frags (units 1,3)
        MMA(aQ, b1, 0);                           // cluster B (kh1 mh0)
        FENCE; __builtin_amdgcn_s_barrier(); FENCE;
        STAGE_MID(cur, t + 2);                    // overwrites B + A units 0,2
        LD_A(aQ, cur, 1, 1);                      // phase-D frags (units 1,3)
        MMA(aP, b0, 1);                           // cluster C (kh0 mh1)
        // tail: retire MID(t+1) (issued 1 tile ago), prefetch next phase-A
        asm volatile("s_waitcnt vmcnt(8)" ::: "memory");
        LD_B(b0, cur ^ 1, 0); LD_A(aP, cur ^ 1, 0, 0);
        MMA(aQ, b1, 1);                           // cluster D (kh1 mh1)
        FENCE; __builtin_amdgcn_s_barrier(); FENCE;
        STAGE_END(cur, t + 2);                    // overwrites A units 1,3
        cur ^= 1;
    }
    // penultimate tile: no staging; waits (8, 2)
    asm volatile("s_waitcnt vmcnt(8)" ::: "memory");
    FENCE; __builtin_amdgcn_s_barrier(); FENCE;
    LD_B(b1, cur, 1); LD_A(aQ, cur, 1, 0);
    MMA(aP, b0, 0);
    LD_A(aP, cur, 0, 1);
    MMA(aQ, b1, 0);
    LD_A(aQ, cur, 1, 1);
    MMA(aP, b0, 1);
    asm volatile("s_waitcnt vmcnt(2)" ::: "memory");   // retire MID(last)
    LD_B(b0, cur ^ 1, 0); LD_A(aP, cur ^ 1, 0, 0);
    MMA(aQ, b1, 1);
    cur ^= 1;
    // last tile
    asm volatile("s_waitcnt vmcnt(0)" ::: "memory");
    FENCE; __builtin_amdgcn_s_barrier(); FENCE;
    LD_B(b1, cur, 1); LD_A(aQ, cur, 1, 0);
    MMA(aP, b0, 0);
    LD_A(aP, cur, 0, 1);
    MMA(aQ, b1, 0);
    LD_A(aQ, cur, 1, 1);
    MMA(aP, b0, 1);
    MMA(aQ, b1, 1);
#undef MMA
#undef LD_A
#undef LD_B
#undef STAGE_MID
#undef STAGE_END
#undef STG_A
#undef STG_B

    // epilogue. C/D: col = ln&15, row = (ln>>4)*4 + r
    const int rb = q * 4;
    if constexpr (EPI == 2) {
        __syncthreads();                       // all LDS reads done; reuse lds
        u64* smin = (u64*)lds;
        if (tid < 256) smin[tid] = ~0ull;
        __syncthreads();
        #pragma unroll
        for (int m = 0; m < 8; ++m) {
            #pragma unroll
            for (int r = 0; r < 4; ++r) {
                u64 best = ~0ull;
                #pragma unroll
                for (int n = 0; n < 4; ++n) {
                    const int col = bn + wc * 64 + n * 16 + fr;
                    const float s = fmaf(-2.f, acc[m][n][r], bias[col]);
                    const u64 pv =
                        ((u64)float_orderable(s) << 32) | (unsigned)col;
                    best = pv < best ? pv : best;
                }
                #pragma unroll
                for (int msk = 1; msk <= 8; msk <<= 1) {
                    const u64 o = __shfl_xor(best, msk);
                    best = o < best ? o : best;
                }
                if (fr == 0)
                    atomicMin(&smin[wr * 128 + m * 16 + rb + r], best);
            }
        }
        __syncthreads();
        if (tid < 256) atomicMin(&packed[bm + tid], smin[tid]);
    } else {
        #pragma unroll
        for (int m = 0; m < 8; ++m) {
            const int row = bm + wr * 128 + m * 16 + rb;
            #pragma unroll
            for (int n = 0; n < 4; ++n) {
                const int col = bn + wc * 64 + n * 16 + fr;
                if (EPI == 3) {
                    #pragma unroll
                    for (int r = 0; r < 4; ++r)
                        Cf[(size_t)(row + r) * N + col] = acc[m][n][r];
                } else if (col < N) {
                    const float bv = bias[col];
                    #pragma unroll
                    for (int r = 0; r < 4; ++r)
                        Cf[(size_t)(row + r) * N + col] = acc[m][n][r] + bv;
                }
            }
        }
    }
}

// ---------------------------------------------------------------------------
// 128x128 m97-style kernel for the small/medium GEMMs.
// EPI: 0 = +bias, 1 = tanh(+bias). WB/WF: bf16/f32 C writes.
// ---------------------------------------------------------------------------
template<int EPI, int WB, int WF>
__global__ __launch_bounds__(256, 2) void mfma_gemm(
    const u16* __restrict__ A, const u16* __restrict__ Bt,
    const float* __restrict__ bias, float* __restrict__ Cf,
    u16* __restrict__ Cb, int M, int N, int K)
{
    __shared__ u16 As[128 * 32];
    __shared__ u16 Bs[128 * 32];
    const int tid = threadIdx.x;
    const int wv = tid >> 6;
    const int ln = tid & 63;
    const int bm = blockIdx.y * 128;
    const int bn = blockIdx.x * 128;

    const int srow = wv * 32 + (ln >> 2);
    const int skel = (ln & 3) * 8;
    const u16* Ap0 = A + (size_t)(bm + srow) * K + skel;
    const u16* Ap1 = Ap0 + (size_t)16 * K;
    const u16* Bp0 = Bt + (size_t)(bn + srow) * K + skel;
    const u16* Bp1 = Bp0 + (size_t)16 * K;
    u16* lA0 = As + wv * 1024;
    u16* lA1 = lA0 + 512;
    u16* lB0 = Bs + wv * 1024;
    u16* lB1 = lB0 + 512;

    const int wr = wv >> 1, wc = wv & 1;
    const int fr = ln & 15;
    const int kg = (ln >> 4) * 8;
    const u16* Afp = As + (wr * 64 + fr) * 32 + kg;
    const u16* Bfp = Bs + (wc * 64 + fr) * 32 + kg;

    v4f acc[4][4];
    #pragma unroll
    for (int m = 0; m < 4; ++m)
        #pragma unroll
        for (int n = 0; n < 4; ++n) acc[m][n] = (v4f)(0.f);

    for (int k0 = 0; k0 < K; k0 += 32) {
        __syncthreads();
        gload_lds16(Ap0 + k0, lA0);
        gload_lds16(Ap1 + k0, lA1);
        gload_lds16(Bp0 + k0, lB0);
        gload_lds16(Bp1 + k0, lB1);
        __syncthreads();
        v8s a[4], b[4];
        #pragma unroll
        for (int m = 0; m < 4; ++m) a[m] = *(const v8s*)(Afp + m * 512);
        #pragma unroll
        for (int n = 0; n < 4; ++n) b[n] = *(const v8s*)(Bfp + n * 512);
        #pragma unroll
        for (int m = 0; m < 4; ++m)
            #pragma unroll
            for (int n = 0; n < 4; ++n)
                acc[m][n] = __builtin_amdgcn_mfma_f32_16x16x32_bf16(
                    a[m], b[n], acc[m][n], 0, 0, 0);
    }

    const int rb = (ln >> 4) * 4;
    #pragma unroll
    for (int m = 0; m < 4; ++m) {
        const int row = bm + wr * 64 + m * 16 + rb;
        #pragma unroll
        for (int n = 0; n < 4; ++n) {
            const int col = bn + wc * 64 + n * 16 + fr;
            if (col < N) {
                const float bv = bias[col];
                #pragma unroll
                for (int r = 0; r < 4; ++r) {
                    float v = acc[m][n][r] + bv;
                    if (EPI == 1) v = tanhf(v);
                    if (WF) Cf[(size_t)(row + r) * N + col] = v;
                    if (WB) Cb[(size_t)(row + r) * N + col] = f2b(v);
                }
            }
        }
    }
}

// out[i] = bf16(tanh(P0+P1+P2+P3+bias)), 8 elems/thread. cs = chunk stride.
__global__ __launch_bounds__(256) void reduce_tanh4(
    const float* __restrict__ P, const float* __restrict__ bias,
    u16* __restrict__ out, long n8, int N, size_t cs)
{
    const long stride = (long)gridDim.x * 256;
    for (long i = (long)blockIdx.x * 256 + threadIdx.x; i < n8; i += stride) {
        const size_t e0 = (size_t)i * 8;
        const int col = (int)(e0 & (size_t)(N - 1));
        float4 s0 = *(const float4*)(P + e0);
        float4 s1 = *(const float4*)(P + e0 + 4);
        #pragma unroll
        for (int c = 1; c < 4; ++c) {
            const float4 a = *(const float4*)(P + c * cs + e0);
            const float4 b = *(const float4*)(P + c * cs + e0 + 4);
            s0.x += a.x; s0.y += a.y; s0.z += a.z; s0.w += a.w;
            s1.x += b.x; s1.y += b.y; s1.z += b.z; s1.w += b.w;
        }
        const float4 bv0 = *(const float4*)(bias + col);
        const float4 bv1 = *(const float4*)(bias + col + 4);
        v8s o;
        o[0] = (short)f2b(tanhf(s0.x + bv0.x));
        o[1] = (short)f2b(tanhf(s0.y + bv0.y));
        o[2] = (short)f2b(tanhf(s0.z + bv0.z));
        o[3] = (short)f2b(tanhf(s0.w + bv0.w));
        o[4] = (short)f2b(tanhf(s1.x + bv1.x));
        o[5] = (short)f2b(tanhf(s1.y + bv1.y));
        o[6] = (short)f2b(tanhf(s1.z + bv1.z));
        o[7] = (short)f2b(tanhf(s1.w + bv1.w));
        *(v8s*)(out + e0) = o;
    }
}

// x [4096][20000] f32 -> xb [4096][20032] bf16, zero-padded. 1 block per row.
__global__ __launch_bounds__(256) void conv_pad_x(
    const float* __restrict__ in, u16* __restrict__ out)
{
    const int row = blockIdx.x;
    const float* src = in + (size_t)row * 20000;
    u16* dst = out + (size_t)row * 20032;
    for (int j = threadIdx.x; j < 2504; j += 256) {
        v8s o;
        if (j < 2500) {
            const float4 a = *(const float4*)(src + j * 8);
            const float4 b = *(const float4*)(src + j * 8 + 4);
            o[0] = (short)f2b(a.x); o[1] = (short)f2b(a.y);
            o[2] = (short)f2b(a.z); o[3] = (short)f2b(a.w);
            o[4] = (short)f2b(b.x); o[5] = (short)f2b(b.y);
            o[6] = (short)f2b(b.z); o[7] = (short)f2b(b.w);
        } else {
            o = (v8s)(short(0));
        }
        *(v8s*)(dst + j * 8) = o;
    }
}

// f32 -> bf16 elementwise, 8/thread. n8 = n/8.
__global__ __launch_bounds__(256) void conv_bf16(
    const float* __restrict__ in, u16* __restrict__ out, long n8)
{
    const long stride = (long)gridDim.x * 256;
    for (long i = (long)blockIdx.x * 256 + threadIdx.x; i < n8; i += stride) {
        const float4 a = ((const float4*)in)[i * 2];
        const float4 b = ((const float4*)in)[i * 2 + 1];
        v8s o;
        o[0] = (short)f2b(a.x); o[1] = (short)f2b(a.y);
        o[2] = (short)f2b(a.z); o[3] = (short)f2b(a.w);
        o[4] = (short)f2b(b.x); o[5] = (short)f2b(b.y);
        o[6] = (short)f2b(b.z); o[7] = (short)f2b(b.w);
        *(v8s*)(out + i * 8) = o;
    }
}

// W[K][N] f32 -> Wt[N][Kp] bf16, rows k>=K zero-filled. block (32,8).
__global__ __launch_bounds__(256) void trans_bf16p(
    const float* __restrict__ W, u16* __restrict__ Wt, int K, int N, int Kp)
{
    __shared__ float t[32][33];
    const int tx = threadIdx.x, ty = threadIdx.y;
    const int n0 = blockIdx.x * 32, k0 = blockIdx.y * 32;
    #pragma unroll
    for (int i = 0; i < 32; i += 8) {
        const int n = n0 + tx;
        const int k = k0 + ty + i;
        t[ty + i][tx] = (n < N && k < K) ? W[(size_t)k * N + n] : 0.f;
    }
    __syncthreads();
    #pragma unroll
    for (int i = 0; i < 32; i += 8) {
        const int n = n0 + ty + i;
        if (n < N) Wt[(size_t)n * Kp + k0 + tx] = f2b(t[tx][ty + i]);
    }
}

// cnorm[k] = ||codebook[k]||^2 (f32), one wave per row.
__global__ __launch_bounds__(64) void cnorm_k(
    const float* __restrict__ CB, float* __restrict__ cn)
{
    const float* row = CB + (size_t)blockIdx.x * 512;
    float s = 0.f;
    #pragma unroll
    for (int u = 0; u < 8; ++u) {
        const float v = row[threadIdx.x + 64 * u];
        s = fmaf(v, v, s);
    }
    #pragma unroll
    for (int m = 32; m; m >>= 1) s += __shfl_down(s, m);
    if (threadIdx.x == 0) cn[blockIdx.x] = s;
}

__global__ void init_packed(u64* __restrict__ p)
{
    p[blockIdx.x * 256 + threadIdx.x] = ~0ull;
}

// gather q rows -> qout (f32, d_out) + qb (bf16, decoder input);
// block partials of sum((q-z)^2) in f64.
__global__ __launch_bounds__(256) void quant_loss(
    const u64* __restrict__ packed, const float* __restrict__ CB,
    const float* __restrict__ Z, float* __restrict__ qout,
    u16* __restrict__ qb, double* __restrict__ partials)
{
    const int gid = blockIdx.x * 256 + threadIdx.x;
    const int i = gid >> 7;
    const int j = (gid & 127) << 2;
    const int k = (int)(packed[i] & 0xffffffffull);
    const float4 c = *(const float4*)(CB + (size_t)k * 512 + j);
    const float4 z = *(const float4*)(Z + (size_t)i * 512 + j);
    const size_t o = (size_t)i * 512 + j;
    qout[o + 0] = c.x; qout[o + 1] = c.y; qout[o + 2] = c.z; qout[o + 3] = c.w;
    qb[o + 0] = f2b(c.x); qb[o + 1] = f2b(c.y);
    qb[o + 2] = f2b(c.z); qb[o + 3] = f2b(c.w);
    const float d0 = c.x - z.x, d1 = c.y - z.y, d2 = c.z - z.z, d3 = c.w - z.w;
    float local = d0 * d0 + d1 * d1 + d2 * d2 + d3 * d3;
    #pragma unroll
    for (int m = 32; m; m >>= 1) local += __shfl_down(local, m);
    __shared__ float wsum[4];
    if ((threadIdx.x & 63) == 0) wsum[threadIdx.x >> 6] = local;
    __syncthreads();
    if (threadIdx.x == 0)
        partials[blockIdx.x] = (double)wsum[0] + (double)wsum[1] +
                               (double)wsum[2] + (double)wsum[3];
}

__global__ __launch_bounds__(256) void loss_final(
    const double* __restrict__ partials, float* __restrict__ out)
{
    double s = 0.0;
    for (int u = threadIdx.x; u < 2048; u += 256) s += partials[u];
    #pragma unroll
    for (int m = 32; m; m >>= 1) s += __shfl_down(s, m);
    __shared__ double ws[4];
    if ((threadIdx.x & 63) == 0) ws[threadIdx.x >> 6] = s;
    __syncthreads();
    if (threadIdx.x == 0)
        out[0] = (float)(1.25 * (ws[0] + ws[1] + ws[2] + ws[3]) / 2097152.0);
}

extern "C" void kernel_launch(void* const* d_in, const int* in_sizes, int n_in,
                              void* d_out, int out_size, void* d_ws, size_t ws_size,
                              hipStream_t stream)
{
    const float* x  = (const float*)d_in[0];
    const float* W1 = (const float*)d_in[1];
    const float* b1 = (const float*)d_in[2];
    const float* W2 = (const float*)d_in[3];
    const float* b2 = (const float*)d_in[4];
    const float* W3 = (const float*)d_in[5];
    const float* b3 = (const float*)d_in[6];
    const float* CB = (const float*)d_in[7];
    const float* W4 = (const float*)d_in[8];
    const float* b4 = (const float*)d_in[9];
    const float* W5 = (const float*)d_in[10];
    const float* b5 = (const float*)d_in[11];
    const float* W6 = (const float*)d_in[12];
    const float* b6 = (const float*)d_in[13];

    float* out  = (float*)d_out;
    float* xrec = out + 1;
    float* qout = out + 1 + (size_t)4096 * 20000;

    // scratch inside d_out's x_recon region (dead until final GEMM):
    u16*   xb    = (u16*)((char*)d_out + 16);                 // [4096][20032] bf16
    float* PART1 = (float*)((char*)d_out + 164102160);        // 4x[4096][2048] f32

    char* ws = (char*)d_ws;
    u16* WT16 = (u16*)(ws + 0);           // Wt1 [2048][20032] / Wt6 [20224][2048]
    u16* WT2  = (u16*)(ws + 82837504);    // [1024][2048]
    u16* WT3  = (u16*)(ws + 87031808);    // [512][1024]
    u16* CBB  = (u16*)(ws + 88080384);    // [8192][512]
    u16* WT4  = (u16*)(ws + 96468992);    // [1024][512]
    u16* WT5  = (u16*)(ws + 97517568);    // [2048][1024]
    u16* ACT1 = (u16*)(ws + 101711872);   // [4096][2048] z1, later h2
    u16* ACT2 = (u16*)(ws + 118489088);   // [4096][1024] z2, later h1
    float* Z3F = (float*)(ws + 126877696); // [4096][512]
    u16* Z3B  = (u16*)(ws + 135266304);   // [4096][512]
    u16* QB   = (u16*)(ws + 139460608);   // [4096][512]
    float* CN = (float*)(ws + 143654912);
    u64* PACKED = (u64*)(ws + 143687680);
    double* PART = (double*)(ws + 143720448);

    const dim3 blk(256);

    // ---- precompute: bf16 conversions + weight transposes ----
    conv_pad_x<<<dim3(4096), blk, 0, stream>>>(x, xb);
    conv_bf16<<<dim3(2048), blk, 0, stream>>>(CB, CBB, 524288L);
    trans_bf16p<<<dim3(64, 626), dim3(32, 8), 0, stream>>>(W1, WT16, 20000, 2048, 20032);
    trans_bf16p<<<dim3(32, 64),  dim3(32, 8), 0, stream>>>(W2, WT2, 2048, 1024, 2048);
    trans_bf16p<<<dim3(16, 32),  dim3(32, 8), 0, stream>>>(W3, WT3, 1024, 512, 1024);
    trans_bf16p<<<dim3(32, 16),  dim3(32, 8), 0, stream>>>(W4, WT4, 512, 1024, 512);
    trans_bf16p<<<dim3(64, 32),  dim3(32, 8), 0, stream>>>(W5, WT5, 1024, 2048, 1024);
    cnorm_k<<<dim3(8192), dim3(64), 0, stream>>>(CB, CN);
    init_packed<<<dim3(16), blk, 0, stream>>>(PACKED);

    // ---- encoder ----
    // GEMM1: 256^2 tile, split-K over 4 chunks (8*16*4 = 512 blocks)
    gemm256<3><<<dim3(8, 16, 4), dim3(512), 131072, stream>>>(
        xb, WT16, nullptr, PART1, nullptr, 4096, 2048, 20032, 20032, 20032);
    reduce_tanh4<<<dim3(4096), blk, 0, stream>>>(
        PART1, b1, ACT1, 1048576L, 2048, (size_t)4096 * 2048);
    // Wt1 dead; transpose W6 into the same arena (stream-ordered)
    trans_bf16p<<<dim3(625, 64), dim3(32, 8), 0, stream>>>(W6, WT16, 2048, 20000, 2048);
    mfma_gemm<1, 1, 0><<<dim3(8, 32), blk, 0, stream>>>(
        ACT1, WT2, b2, nullptr, ACT2, 4096, 1024, 2048);
    mfma_gemm<1, 1, 1><<<dim3(4, 32), blk, 0, stream>>>(
        ACT2, WT3, b3, Z3F, Z3B, 4096, 512, 1024);

    // ---- VQ: 256^2 score GEMM with fused argmin, then gather + loss ----
    gemm256<2><<<dim3(32, 16), dim3(512), 131072, stream>>>(
        Z3B, CBB, CN, nullptr, PACKED, 4096, 8192, 512, 512, 512);
    quant_loss<<<dim3(2048), blk, 0, stream>>>(PACKED, CB, Z3F, qout, QB, PART);
    loss_final<<<dim3(1), blk, 0, stream>>>(PART, out);

    // ---- decoder ----
    mfma_gemm<1, 1, 0><<<dim3(8, 32), blk, 0, stream>>>(
        QB, WT4, b4, nullptr, ACT2, 4096, 1024, 512);
    mfma_gemm<1, 1, 0><<<dim3(16, 32), blk, 0, stream>>>(
        ACT2, WT5, b5, nullptr, ACT1, 4096, 2048, 1024);
    // GEMM6: 256^2 tile, grid 79x16 = 1264 blocks (padded Wt6 rows readable)
    gemm256<0><<<dim3(79, 16), dim3(512), 131072, stream>>>(
        ACT1, WT16, b6, xrec, nullptr, 4096, 20000, 2048, 2048, 2048);
}

// Round 7
// 1185.157 us; speedup vs baseline: 1.0399x; 1.0399x over previous
//
#include <hip/hip_runtime.h>
#include <hip/hip_bf16.h>
#include <math.h>

// ---------------------------------------------------------------------------
// VQ-VAE forward. B=4096, G=20000, dims 2048/1024/512, K=8192 codes.
// Round 7: GEMM1 + GEMM6 on MX-fp8 (mfma_scale_f32_16x16x128_f8f6f4, identity
// scales, pre-scaled weights: W1 x 2^12, W6 x 2^10, h2 x 2^16; compensation
// folded into f32 epilogues). Hand-rolled RNE f32->e4m3 (FTZ<2^-6, clamp 448).
// Same 3-barrier counted-vmcnt 256^2 schedule, BK=128 (tile bytes identical
// to bf16 BK=64 so staging/swizzle algebra carries over). VQ reverted to the
// 128^2 fused-argmin kernel (r6 showed gemm256@K=512 was a regression).
// ---------------------------------------------------------------------------

typedef short v8s __attribute__((ext_vector_type(8)));
typedef float v4f __attribute__((ext_vector_type(4)));
typedef int   v8i __attribute__((ext_vector_type(8)));
typedef int   v4i __attribute__((ext_vector_type(4)));
typedef unsigned short u16;
typedef unsigned char  u8;
typedef unsigned long long u64;

typedef const unsigned int __attribute__((address_space(1)))* as1p;
typedef unsigned int __attribute__((address_space(3)))* as3p;

__device__ __forceinline__ void gload_lds16(const void* g, void* l) {
    __builtin_amdgcn_global_load_lds((as1p)g, (as3p)l, 16, 0, 0);
}

__device__ __forceinline__ u16 f2b(float f) {
    return __builtin_bit_cast(u16, __float2bfloat16(f));
}

// f32 -> OCP e4m3fn, RNE on normals, FTZ below 2^-6, clamp to 448 (no NaN out)
__device__ __forceinline__ u8 f2e4m3(float f) {
    unsigned u = __float_as_uint(f);
    unsigned s = (u >> 24) & 0x80u;
    unsigned a = u & 0x7FFFFFFFu;
    if (a < 0x3C800000u) return (u8)s;            // |f| < 2^-6 -> signed zero
    if (a > 0x43E00000u) a = 0x43E00000u;         // clamp to 448
    a += ((a >> 20) & 1u) + 0x7FFFFu;             // RNE to 3 mantissa bits
    if (a > 0x43E00000u) a = 0x43E00000u;         // re-clamp post-round
    unsigned e = (a >> 23) - 120u;                // e4m3 exponent (1..15)
    unsigned m = (a >> 20) & 7u;
    return (u8)(s | (e << 3) | m);
}

__device__ __forceinline__ unsigned int float_orderable(float f)
{
    unsigned int b = __float_as_uint(f);
    return (b & 0x80000000u) ? ~b : (b | 0x80000000u);
}

#define FENCE asm volatile("" ::: "memory")

// ---------------------------------------------------------------------------
// fp8 256x256 tile, 512 threads (8 waves = 2Mx4N), BK=128, double-buffered
// LDS (128 KB), 2 MFMA clusters/tile, counted vmcnt, slot-XOR swizzle.
// A,Bt are e4m3 bytes; sA/sB = row strides in BYTES. acc scaled by fscale in
// the epilogue (identity HW scales). EPI: 0 = fscale*acc + bias, f32 store
// (col<N masked); 3 = raw f32 partials, K split over blockIdx.z.
// K%128==0; M%256==0; >=2 K-tiles per block; nwg%8==0.
// ---------------------------------------------------------------------------
template<int EPI>
__global__ __launch_bounds__(512, 1) void gemm256f8(
    const u8* __restrict__ A, const u8* __restrict__ Bt,
    const float* __restrict__ bias, float* __restrict__ Cf,
    float fscale, int M, int N, int K, int sA, int sB)
{
    extern __shared__ char lds[];   // [2][A 32K | B 32K] = 128 KB

    const int gx = gridDim.x, gy = gridDim.y, gz = gridDim.z;
    const int nwg = gx * gy * gz;
    int flat = (blockIdx.z * gy + blockIdx.y) * gx + blockIdx.x;
    flat = (flat & 7) * (nwg >> 3) + (flat >> 3);
    const int bx = flat % gx;
    const int rem = flat / gx;
    const int by = rem % gy;
    const int bz = rem / gy;
    const int bm = by * 256, bn = bx * 256;

    const int tiles = K >> 7;
    int t0 = 0, t1 = tiles;
    if (EPI == 3) {
        const int qz = tiles / gz, rz = tiles % gz;
        t0 = bz * qz + (bz < rz ? bz : rz);
        t1 = t0 + qz + (bz < rz ? 1 : 0);
        Cf += (size_t)bz * ((size_t)M * N);
    }

    const int tid = threadIdx.x;
    const int wv = tid >> 6, ln = tid & 63;

    // staging: 1KB chunk = 8 rows x 128B; source slot pre-swizzled (rule #21)
    const int srow = wv * 8 + (ln >> 3);
    const int scol = ((ln & 7) ^ ((ln >> 3) & 7)) * 16;
    const u8* Asrc = A + (size_t)(bm + srow) * sA + scol;
    const u8* Bsrc = Bt + (size_t)(bn + srow) * sB + scol;
    char* stA = lds + wv * 1024;
    char* stB = lds + 32768 + wv * 1024;

#define STG_A(P, KT, J)                                                       \
    gload_lds16(Asrc + ((size_t)(KT) << 7) + (size_t)(J) * 64 * sA,           \
                stA + (P) * 65536 + (J) * 8192)
#define STG_B(P, KT, J)                                                       \
    gload_lds16(Bsrc + ((size_t)(KT) << 7) + (size_t)(J) * 64 * sB,           \
                stB + (P) * 65536 + (J) * 8192)
#define STAGE_MID(P, KT)                                                      \
    { STG_B(P, KT, 0); STG_B(P, KT, 1); STG_B(P, KT, 2); STG_B(P, KT, 3);     \
      STG_A(P, KT, 0); STG_A(P, KT, 2); }
#define STAGE_END(P, KT)                                                      \
    { STG_A(P, KT, 1); STG_A(P, KT, 3); }

    // fragment bases: lane ln -> row fr, k-bytes [q*32, q*32+32) as two
    // swizzled 16B slots
    const int wr = wv >> 2, wc = wv & 3;
    const int fr = ln & 15, q = ln >> 4;
    const int sw8 = fr & 7;
    const int cbLo = ((2 * q) ^ sw8) << 4;
    const int cbHi = ((2 * q + 1) ^ sw8) << 4;
    const char* Afrag = lds + (size_t)(wr * 128 + fr) * 128;
    const char* Bfrag = lds + 32768 + (size_t)(wc * 64 + fr) * 128;

    v4f acc[8][4];
    #pragma unroll
    for (int m = 0; m < 8; ++m)
        #pragma unroll
        for (int n = 0; n < 4; ++n) acc[m][n] = (v4f)(0.f);

    v8i aP[4], aQ[4], b[4];

#define LD_A(REG, PP, MH)                                                     \
    {                                                                         \
        const char* Ab_ = Afrag + (PP) * 65536;                               \
        _Pragma("unroll")                                                     \
        for (int m = 0; m < 4; ++m) {                                         \
            v4i lo_ = *(const v4i*)(Ab_ + ((MH) * 4 + m) * 2048 + cbLo);      \
            v4i hi_ = *(const v4i*)(Ab_ + ((MH) * 4 + m) * 2048 + cbHi);      \
            v8i f_;                                                           \
            _Pragma("unroll")                                                 \
            for (int z = 0; z < 4; ++z) { f_[z] = lo_[z]; f_[z + 4] = hi_[z]; } \
            REG[m] = f_;                                                      \
        }                                                                     \
    }
#define LD_B(PP)                                                              \
    {                                                                         \
        const char* Bb_ = Bfrag + (PP) * 65536;                               \
        _Pragma("unroll")                                                     \
        for (int n = 0; n < 4; ++n) {                                         \
            v4i lo_ = *(const v4i*)(Bb_ + n * 2048 + cbLo);                   \
            v4i hi_ = *(const v4i*)(Bb_ + n * 2048 + cbHi);                   \
            v8i f_;                                                           \
            _Pragma("unroll")                                                 \
            for (int z = 0; z < 4; ++z) { f_[z] = lo_[z]; f_[z + 4] = hi_[z]; } \
            b[n] = f_;                                                        \
        }                                                                     \
    }
#define MMA(AR, MH)                                                           \
    {                                                                         \
        __builtin_amdgcn_s_setprio(1);                                        \
        _Pragma("unroll")                                                     \
        for (int m = 0; m < 4; ++m)                                           \
            _Pragma("unroll")                                                 \
            for (int n = 0; n < 4; ++n)                                       \
                acc[(MH) * 4 + m][n] =                                        \
                    __builtin_amdgcn_mfma_scale_f32_16x16x128_f8f6f4(         \
                        AR[m], b[n], acc[(MH) * 4 + m][n],                    \
                        0, 0, 0, 0x7F7F7F7F, 0, 0x7F7F7F7F);                  \
        __builtin_amdgcn_s_setprio(0);                                        \
    }

    // prologue: stage 2 tiles; retire MID(t0); load tile-t0 mh0 A-frags
    STAGE_MID(0, t0); STAGE_END(0, t0);
    STAGE_MID(1, t0 + 1); STAGE_END(1, t0 + 1);
    asm volatile("s_waitcnt vmcnt(10)" ::: "memory");
    FENCE; __builtin_amdgcn_s_barrier(); FENCE;
    LD_A(aP, 0, 0);

    int cur = 0;
    for (int t = t0; t < t1 - 2; ++t) {
        // entry: retire END(t) (outstanding 10 -> 8)
        asm volatile("s_waitcnt vmcnt(8)" ::: "memory");
        FENCE; __builtin_amdgcn_s_barrier(); FENCE;
        LD_B(cur); LD_A(aQ, cur, 1);
        MMA(aP, 0);
        FENCE; __builtin_amdgcn_s_barrier(); FENCE;   // B+A02(cur) dead
        STAGE_MID(cur, t + 2);
        asm volatile("s_waitcnt vmcnt(8)" ::: "memory");  // retire MID(t+1)
        MMA(aQ, 1);
        FENCE; __builtin_amdgcn_s_barrier(); FENCE;   // all MID(t+1) retired
        LD_A(aP, cur ^ 1, 0);                         // next-tile mh0 frags
        STAGE_END(cur, t + 2);                        // overwrites A13(cur)
        cur ^= 1;
    }
    // penultimate tile (no staging)
    asm volatile("s_waitcnt vmcnt(8)" ::: "memory");  // retire END(penult)
    FENCE; __builtin_amdgcn_s_barrier(); FENCE;
    LD_B(cur); LD_A(aQ, cur, 1);
    MMA(aP, 0);
    MMA(aQ, 1);
    cur ^= 1;
    // last tile
    asm volatile("s_waitcnt vmcnt(0)" ::: "memory");
    FENCE; __builtin_amdgcn_s_barrier(); FENCE;
    LD_B(cur); LD_A(aP, cur, 0); LD_A(aQ, cur, 1);
    MMA(aP, 0);
    MMA(aQ, 1);
#undef MMA
#undef LD_A
#undef LD_B
#undef STAGE_MID
#undef STAGE_END
#undef STG_A
#undef STG_B

    // epilogue. C/D: col = ln&15, row = (ln>>4)*4 + r
    const int rb = q * 4;
    #pragma unroll
    for (int m = 0; m < 8; ++m) {
        const int row = bm + wr * 128 + m * 16 + rb;
        #pragma unroll
        for (int n = 0; n < 4; ++n) {
            const int col = bn + wc * 64 + n * 16 + fr;
            if (EPI == 3) {
                #pragma unroll
                for (int r = 0; r < 4; ++r)
                    Cf[(size_t)(row + r) * N + col] = acc[m][n][r];
            } else if (col < N) {
                const float bv = bias[col];
                #pragma unroll
                for (int r = 0; r < 4; ++r)
                    Cf[(size_t)(row + r) * N + col] =
                        fmaf(acc[m][n][r], fscale, bv);
            }
        }
    }
}

// ---------------------------------------------------------------------------
// 128x128 bf16 kernel for the small/medium GEMMs + fused-argmin VQ.
// EPI: 0 = +bias, 1 = tanh(+bias), 2 = VQ argmin (score = bias - 2*acc,
// packed u64 atomicMin per row, no C write). WB/WF: bf16/f32 writes.
// W8: write e4m3(v * s8) to C8 (decoder h2 path).
// ---------------------------------------------------------------------------
template<int EPI, int WB, int WF, int W8>
__global__ __launch_bounds__(256, 2) void mfma_gemm(
    const u16* __restrict__ A, const u16* __restrict__ Bt,
    const float* __restrict__ bias, float* __restrict__ Cf,
    u16* __restrict__ Cb, u8* __restrict__ C8, u64* __restrict__ packed,
    float s8, int M, int N, int K)
{
    __shared__ u16 As[128 * 32];
    __shared__ u16 Bs[128 * 32];
    const int tid = threadIdx.x;
    const int wv = tid >> 6;
    const int ln = tid & 63;
    const int bm = blockIdx.y * 128;
    const int bn = blockIdx.x * 128;

    const int srow = wv * 32 + (ln >> 2);
    const int skel = (ln & 3) * 8;
    const u16* Ap0 = A + (size_t)(bm + srow) * K + skel;
    const u16* Ap1 = Ap0 + (size_t)16 * K;
    const u16* Bp0 = Bt + (size_t)(bn + srow) * K + skel;
    const u16* Bp1 = Bp0 + (size_t)16 * K;
    u16* lA0 = As + wv * 1024;
    u16* lA1 = lA0 + 512;
    u16* lB0 = Bs + wv * 1024;
    u16* lB1 = lB0 + 512;

    const int wr = wv >> 1, wc = wv & 1;
    const int fr = ln & 15;
    const int kg = (ln >> 4) * 8;
    const u16* Afp = As + (wr * 64 + fr) * 32 + kg;
    const u16* Bfp = Bs + (wc * 64 + fr) * 32 + kg;

    v4f acc[4][4];
    #pragma unroll
    for (int m = 0; m < 4; ++m)
        #pragma unroll
        for (int n = 0; n < 4; ++n) acc[m][n] = (v4f)(0.f);

    for (int k0 = 0; k0 < K; k0 += 32) {
        __syncthreads();
        gload_lds16(Ap0 + k0, lA0);
        gload_lds16(Ap1 + k0, lA1);
        gload_lds16(Bp0 + k0, lB0);
        gload_lds16(Bp1 + k0, lB1);
        __syncthreads();
        v8s a[4], b[4];
        #pragma unroll
        for (int m = 0; m < 4; ++m) a[m] = *(const v8s*)(Afp + m * 512);
        #pragma unroll
        for (int n = 0; n < 4; ++n) b[n] = *(const v8s*)(Bfp + n * 512);
        #pragma unroll
        for (int m = 0; m < 4; ++m)
            #pragma unroll
            for (int n = 0; n < 4; ++n)
                acc[m][n] = __builtin_amdgcn_mfma_f32_16x16x32_bf16(
                    a[m], b[n], acc[m][n], 0, 0, 0);
    }

    const int rb = (ln >> 4) * 4;

    if constexpr (EPI == 2) {
        __shared__ u64 smin[128];
        if (tid < 128) smin[tid] = ~0ull;
        __syncthreads();
        #pragma unroll
        for (int m = 0; m < 4; ++m) {
            #pragma unroll
            for (int r = 0; r < 4; ++r) {
                u64 best = ~0ull;
                #pragma unroll
                for (int n = 0; n < 4; ++n) {
                    const int col = bn + wc * 64 + n * 16 + fr;
                    const float s = fmaf(-2.f, acc[m][n][r], bias[col]);
                    const u64 pv =
                        ((u64)float_orderable(s) << 32) | (unsigned)col;
                    best = pv < best ? pv : best;
                }
                #pragma unroll
                for (int msk = 1; msk <= 8; msk <<= 1) {
                    const u64 o = __shfl_xor(best, msk);
                    best = o < best ? o : best;
                }
                if (fr == 0) atomicMin(&smin[wr * 64 + m * 16 + rb + r], best);
            }
        }
        __syncthreads();
        if (tid < 128) atomicMin(&packed[bm + tid], smin[tid]);
    } else {
        #pragma unroll
        for (int m = 0; m < 4; ++m) {
            const int row = bm + wr * 64 + m * 16 + rb;
            #pragma unroll
            for (int n = 0; n < 4; ++n) {
                const int col = bn + wc * 64 + n * 16 + fr;
                if (col < N) {
                    const float bv = bias[col];
                    #pragma unroll
                    for (int r = 0; r < 4; ++r) {
                        float v = acc[m][n][r] + bv;
                        if (EPI == 1) v = tanhf(v);
                        if (WF) Cf[(size_t)(row + r) * N + col] = v;
                        if (WB) Cb[(size_t)(row + r) * N + col] = f2b(v);
                        if (W8) C8[(size_t)(row + r) * N + col] = f2e4m3(v * s8);
                    }
                }
            }
        }
    }
}

// out[i] = bf16(tanh((P0+P1+P2+P3)*fs + bias)), 8 elems/thread.
__global__ __launch_bounds__(256) void reduce_tanh4(
    const float* __restrict__ P, const float* __restrict__ bias,
    u16* __restrict__ out, long n8, int N, size_t cs, float fs)
{
    const long stride = (long)gridDim.x * 256;
    for (long i = (long)blockIdx.x * 256 + threadIdx.x; i < n8; i += stride) {
        const size_t e0 = (size_t)i * 8;
        const int col = (int)(e0 & (size_t)(N - 1));
        float4 s0 = *(const float4*)(P + e0);
        float4 s1 = *(const float4*)(P + e0 + 4);
        #pragma unroll
        for (int c = 1; c < 4; ++c) {
            const float4 a = *(const float4*)(P + c * cs + e0);
            const float4 b = *(const float4*)(P + c * cs + e0 + 4);
            s0.x += a.x; s0.y += a.y; s0.z += a.z; s0.w += a.w;
            s1.x += b.x; s1.y += b.y; s1.z += b.z; s1.w += b.w;
        }
        const float4 bv0 = *(const float4*)(bias + col);
        const float4 bv1 = *(const float4*)(bias + col + 4);
        v8s o;
        o[0] = (short)f2b(tanhf(fmaf(s0.x, fs, bv0.x)));
        o[1] = (short)f2b(tanhf(fmaf(s0.y, fs, bv0.y)));
        o[2] = (short)f2b(tanhf(fmaf(s0.z, fs, bv0.z)));
        o[3] = (short)f2b(tanhf(fmaf(s0.w, fs, bv0.w)));
        o[4] = (short)f2b(tanhf(fmaf(s1.x, fs, bv1.x)));
        o[5] = (short)f2b(tanhf(fmaf(s1.y, fs, bv1.y)));
        o[6] = (short)f2b(tanhf(fmaf(s1.z, fs, bv1.z)));
        o[7] = (short)f2b(tanhf(fmaf(s1.w, fs, bv1.w)));
        *(v8s*)(out + e0) = o;
    }
}

// x [4096][20000] f32 -> xb [4096][20096] e4m3, zero-padded. 1 block per row.
__global__ __launch_bounds__(256) void conv_pad_x_f8(
    const float* __restrict__ in, u8* __restrict__ out)
{
    const int row = blockIdx.x;
    const float* src = in + (size_t)row * 20000;
    u8* dst = out + (size_t)row * 20096;
    for (int j = threadIdx.x; j < 2512; j += 256) {
        u64 o = 0;
        if (j < 2500) {
            const float4 a = *(const float4*)(src + j * 8);
            const float4 b = *(const float4*)(src + j * 8 + 4);
            o |= (u64)f2e4m3(a.x) << 0;  o |= (u64)f2e4m3(a.y) << 8;
            o |= (u64)f2e4m3(a.z) << 16; o |= (u64)f2e4m3(a.w) << 24;
            o |= (u64)f2e4m3(b.x) << 32; o |= (u64)f2e4m3(b.y) << 40;
            o |= (u64)f2e4m3(b.z) << 48; o |= (u64)f2e4m3(b.w) << 56;
        }
        *(u64*)(dst + j * 8) = o;
    }
}

// f32 -> bf16 elementwise, 8/thread. n8 = n/8.
__global__ __launch_bounds__(256) void conv_bf16(
    const float* __restrict__ in, u16* __restrict__ out, long n8)
{
    const long stride = (long)gridDim.x * 256;
    for (long i = (long)blockIdx.x * 256 + threadIdx.x; i < n8; i += stride) {
        const float4 a = ((const float4*)in)[i * 2];
        const float4 b = ((const float4*)in)[i * 2 + 1];
        v8s o;
        o[0] = (short)f2b(a.x); o[1] = (short)f2b(a.y);
        o[2] = (short)f2b(a.z); o[3] = (short)f2b(a.w);
        o[4] = (short)f2b(b.x); o[5] = (short)f2b(b.y);
        o[6] = (short)f2b(b.z); o[7] = (short)f2b(b.w);
        *(v8s*)(out + i * 8) = o;
    }
}

// W[K][N] f32 -> Wt[N][Kp] bf16, rows k>=K zero-filled. block (32,8).
__global__ __launch_bounds__(256) void trans_bf16p(
    const float* __restrict__ W, u16* __restrict__ Wt, int K, int N, int Kp)
{
    __shared__ float t[32][33];
    const int tx = threadIdx.x, ty = threadIdx.y;
    const int n0 = blockIdx.x * 32, k0 = blockIdx.y * 32;
    #pragma unroll
    for (int i = 0; i < 32; i += 8) {
        const int n = n0 + tx;
        const int k = k0 + ty + i;
        t[ty + i][tx] = (n < N && k < K) ? W[(size_t)k * N + n] : 0.f;
    }
    __syncthreads();
    #pragma unroll
    for (int i = 0; i < 32; i += 8) {
        const int n = n0 + ty + i;
        if (n < N) Wt[(size_t)n * Kp + k0 + tx] = f2b(t[tx][ty + i]);
    }
}

// W[K][N] f32 -> Wt[N][Kp] e4m3 of (w*scale), rows k>=K zero-filled.
__global__ __launch_bounds__(256) void trans_f8p(
    const float* __restrict__ W, u8* __restrict__ Wt, int K, int N, int Kp,
    float scale)
{
    __shared__ float t[32][33];
    const int tx = threadIdx.x, ty = threadIdx.y;
    const int n0 = blockIdx.x * 32, k0 = blockIdx.y * 32;
    #pragma unroll
    for (int i = 0; i < 32; i += 8) {
        const int n = n0 + tx;
        const int k = k0 + ty + i;
        t[ty + i][tx] = (n < N && k < K) ? W[(size_t)k * N + n] * scale : 0.f;
    }
    __syncthreads();
    #pragma unroll
    for (int i = 0; i < 32; i += 8) {
        const int n = n0 + ty + i;
        if (n < N) Wt[(size_t)n * Kp + k0 + tx] = f2e4m3(t[tx][ty + i]);
    }
}

// cnorm[k] = ||codebook[k]||^2 (f32), one wave per row.
__global__ __launch_bounds__(64) void cnorm_k(
    const float* __restrict__ CB, float* __restrict__ cn)
{
    const float* row = CB + (size_t)blockIdx.x * 512;
    float s = 0.f;
    #pragma unroll
    for (int u = 0; u < 8; ++u) {
        const float v = row[threadIdx.x + 64 * u];
        s = fmaf(v, v, s);
    }
    #pragma unroll
    for (int m = 32; m; m >>= 1) s += __shfl_down(s, m);
    if (threadIdx.x == 0) cn[blockIdx.x] = s;
}

__global__ void init_packed(u64* __restrict__ p)
{
    p[blockIdx.x * 256 + threadIdx.x] = ~0ull;
}

// gather q rows -> qout (f32, d_out) + qb (bf16, decoder input);
// block partials of sum((q-z)^2) in f64.
__global__ __launch_bounds__(256) void quant_loss(
    const u64* __restrict__ packed, const float* __restrict__ CB,
    const float* __restrict__ Z, float* __restrict__ qout,
    u16* __restrict__ qb, double* __restrict__ partials)
{
    const int gid = blockIdx.x * 256 + threadIdx.x;
    const int i = gid >> 7;
    const int j = (gid & 127) << 2;
    const int k = (int)(packed[i] & 0xffffffffull);
    const float4 c = *(const float4*)(CB + (size_t)k * 512 + j);
    const float4 z = *(const float4*)(Z + (size_t)i * 512 + j);
    const size_t o = (size_t)i * 512 + j;
    qout[o + 0] = c.x; qout[o + 1] = c.y; qout[o + 2] = c.z; qout[o + 3] = c.w;
    qb[o + 0] = f2b(c.x); qb[o + 1] = f2b(c.y);
    qb[o + 2] = f2b(c.z); qb[o + 3] = f2b(c.w);
    const float d0 = c.x - z.x, d1 = c.y - z.y, d2 = c.z - z.z, d3 = c.w - z.w;
    float local = d0 * d0 + d1 * d1 + d2 * d2 + d3 * d3;
    #pragma unroll
    for (int m = 32; m; m >>= 1) local += __shfl_down(local, m);
    __shared__ float wsum[4];
    if ((threadIdx.x & 63) == 0) wsum[threadIdx.x >> 6] = local;
    __syncthreads();
    if (threadIdx.x == 0)
        partials[blockIdx.x] = (double)wsum[0] + (double)wsum[1] +
                               (double)wsum[2] + (double)wsum[3];
}

__global__ __launch_bounds__(256) void loss_final(
    const double* __restrict__ partials, float* __restrict__ out)
{
    double s = 0.0;
    for (int u = threadIdx.x; u < 2048; u += 256) s += partials[u];
    #pragma unroll
    for (int m = 32; m; m >>= 1) s += __shfl_down(s, m);
    __shared__ double ws[4];
    if ((threadIdx.x & 63) == 0) ws[threadIdx.x >> 6] = s;
    __syncthreads();
    if (threadIdx.x == 0)
        out[0] = (float)(1.25 * (ws[0] + ws[1] + ws[2] + ws[3]) / 2097152.0);
}

extern "C" void kernel_launch(void* const* d_in, const int* in_sizes, int n_in,
                              void* d_out, int out_size, void* d_ws, size_t ws_size,
                              hipStream_t stream)
{
    const float* x  = (const float*)d_in[0];
    const float* W1 = (const float*)d_in[1];
    const float* b1 = (const float*)d_in[2];
    const float* W2 = (const float*)d_in[3];
    const float* b2 = (const float*)d_in[4];
    const float* W3 = (const float*)d_in[5];
    const float* b3 = (const float*)d_in[6];
    const float* CB = (const float*)d_in[7];
    const float* W4 = (const float*)d_in[8];
    const float* b4 = (const float*)d_in[9];
    const float* W5 = (const float*)d_in[10];
    const float* b5 = (const float*)d_in[11];
    const float* W6 = (const float*)d_in[12];
    const float* b6 = (const float*)d_in[13];

    float* out  = (float*)d_out;
    float* xrec = out + 1;
    float* qout = out + 1 + (size_t)4096 * 20000;

    // scratch inside d_out's x_recon region (dead until final GEMM):
    u8*    XB8   = (u8*)((char*)d_out + 16);            // [4096][20096] e4m3
    float* PART1 = (float*)((char*)d_out + 16 + 82313216);  // 4x[4096][2048] f32

    char* ws = (char*)d_ws;
    u8*  W1T8 = (u8*)(ws + 0);            // [2048][20096] e4m3, later W6T8
    u8*  W6T8 = (u8*)(ws + 0);            // [20224][2048] e4m3 (after GEMM1)
    u16* WT2  = (u16*)(ws + 82837504);    // [1024][2048] bf16
    u16* WT3  = (u16*)(ws + 87031808);    // [512][1024]
    u16* CBB  = (u16*)(ws + 88080384);    // [8192][512]
    u16* WT4  = (u16*)(ws + 96468992);    // [1024][512]
    u16* WT5  = (u16*)(ws + 97517568);    // [2048][1024]
    u16* ACT1 = (u16*)(ws + 101711872);   // [4096][2048] bf16 z1; later h2-fp8
    u8*  H2F8 = (u8*)(ws + 101711872);    // [4096][2048] e4m3 (z1 dead)
    u16* ACT2 = (u16*)(ws + 118489088);   // [4096][1024] z2, later h1
    float* Z3F = (float*)(ws + 126877696); // [4096][512]
    u16* Z3B  = (u16*)(ws + 135266304);   // [4096][512]
    u16* QB   = (u16*)(ws + 139460608);   // [4096][512]
    float* CN = (float*)(ws + 143654912);
    u64* PACKED = (u64*)(ws + 143687680);
    double* PART = (double*)(ws + 143720448);

    const dim3 blk(256);

    // ---- precompute ----
    conv_pad_x_f8<<<dim3(4096), blk, 0, stream>>>(x, XB8);
    conv_bf16<<<dim3(2048), blk, 0, stream>>>(CB, CBB, 524288L);
    trans_f8p<<<dim3(64, 628), dim3(32, 8), 0, stream>>>(
        W1, W1T8, 20000, 2048, 20096, 4096.f);        // W1 x 2^12
    trans_bf16p<<<dim3(32, 64),  dim3(32, 8), 0, stream>>>(W2, WT2, 2048, 1024, 2048);
    trans_bf16p<<<dim3(16, 32),  dim3(32, 8), 0, stream>>>(W3, WT3, 1024, 512, 1024);
    trans_bf16p<<<dim3(32, 16),  dim3(32, 8), 0, stream>>>(W4, WT4, 512, 1024, 512);
    trans_bf16p<<<dim3(64, 32),  dim3(32, 8), 0, stream>>>(W5, WT5, 1024, 2048, 1024);
    cnorm_k<<<dim3(8192), dim3(64), 0, stream>>>(CB, CN);
    init_packed<<<dim3(16), blk, 0, stream>>>(PACKED);

    // ---- encoder ----
    // GEMM1: fp8 256^2, split-K 4 chunks (512 blocks); acc scale 2^-12 in reduce
    gemm256f8<3><<<dim3(8, 16, 4), dim3(512), 131072, stream>>>(
        XB8, W1T8, nullptr, PART1, 1.f, 4096, 2048, 20096, 20096, 20096);
    reduce_tanh4<<<dim3(4096), blk, 0, stream>>>(
        PART1, b1, ACT1, 1048576L, 2048, (size_t)4096 * 2048, 1.f / 4096.f);
    // W1T8 dead; W6 (x 2^10) into the same arena
    trans_f8p<<<dim3(625, 64), dim3(32, 8), 0, stream>>>(
        W6, W6T8, 2048, 20000, 2048, 1024.f);
    mfma_gemm<1, 1, 0, 0><<<dim3(8, 32), blk, 0, stream>>>(
        ACT1, WT2, b2, nullptr, ACT2, nullptr, nullptr, 0.f, 4096, 1024, 2048);
    mfma_gemm<1, 1, 1, 0><<<dim3(4, 32), blk, 0, stream>>>(
        ACT2, WT3, b3, Z3F, Z3B, nullptr, nullptr, 0.f, 4096, 512, 1024);

    // ---- VQ: 128^2 score GEMM with fused argmin, then gather + loss ----
    mfma_gemm<2, 0, 0, 0><<<dim3(64, 32), blk, 0, stream>>>(
        Z3B, CBB, CN, nullptr, nullptr, nullptr, PACKED, 0.f, 4096, 8192, 512);
    quant_loss<<<dim3(2048), blk, 0, stream>>>(PACKED, CB, Z3F, qout, QB, PART);
    loss_final<<<dim3(1), blk, 0, stream>>>(PART, out);

    // ---- decoder ----
    mfma_gemm<1, 1, 0, 0><<<dim3(8, 32), blk, 0, stream>>>(
        QB, WT4, b4, nullptr, ACT2, nullptr, nullptr, 0.f, 4096, 1024, 512);
    // GEMM5 writes h2 as e4m3(h2 * 2^16) for the fp8 final GEMM
    mfma_gemm<1, 0, 0, 1><<<dim3(16, 32), blk, 0, stream>>>(
        ACT2, WT5, b5, nullptr, nullptr, H2F8, nullptr, 65536.f, 4096, 2048, 1024);
    // GEMM6: fp8 256^2, acc scale 2^-26 (h2 2^-16 * W6 2^-10)
    gemm256f8<0><<<dim3(79, 16), dim3(512), 131072, stream>>>(
        H2F8, W6T8, b6, xrec, 1.f / 67108864.f, 4096, 20000, 2048, 2048, 2048);
}

// Round 8
// 1044.779 us; speedup vs baseline: 1.1796x; 1.1344x over previous
//
#include <hip/hip_runtime.h>
#include <hip/hip_bf16.h>
#include <math.h>

// ---------------------------------------------------------------------------
// VQ-VAE forward. B=4096, G=20000, dims 2048/1024/512, K=8192 codes.
// Round 8: GEMM6 reverted to bf16 gemm256 (fp8 version was L2-miss-bound and
// slower: 406 vs 360 us, WRITE 704 vs 331 MB). GEMM1 stays MX-fp8 (identity
// scales, W1 x 2^12 pre-scale, 2^-12 folded into reduce) with split-K 2
// (PART1+reduce traffic halved). Small GEMMs + VQ on the 128^2 bf16 kernel.
// ---------------------------------------------------------------------------

typedef short v8s __attribute__((ext_vector_type(8)));
typedef float v4f __attribute__((ext_vector_type(4)));
typedef int   v8i __attribute__((ext_vector_type(8)));
typedef int   v4i __attribute__((ext_vector_type(4)));
typedef unsigned short u16;
typedef unsigned char  u8;
typedef unsigned long long u64;

typedef const unsigned int __attribute__((address_space(1)))* as1p;
typedef unsigned int __attribute__((address_space(3)))* as3p;

__device__ __forceinline__ void gload_lds16(const void* g, void* l) {
    __builtin_amdgcn_global_load_lds((as1p)g, (as3p)l, 16, 0, 0);
}

__device__ __forceinline__ u16 f2b(float f) {
    return __builtin_bit_cast(u16, __float2bfloat16(f));
}

// f32 -> OCP e4m3fn, RNE on normals, FTZ below 2^-6, clamp to 448
__device__ __forceinline__ u8 f2e4m3(float f) {
    unsigned u = __float_as_uint(f);
    unsigned s = (u >> 24) & 0x80u;
    unsigned a = u & 0x7FFFFFFFu;
    if (a < 0x3C800000u) return (u8)s;
    if (a > 0x43E00000u) a = 0x43E00000u;
    a += ((a >> 20) & 1u) + 0x7FFFFu;
    if (a > 0x43E00000u) a = 0x43E00000u;
    unsigned e = (a >> 23) - 120u;
    unsigned m = (a >> 20) & 7u;
    return (u8)(s | (e << 3) | m);
}

__device__ __forceinline__ unsigned int float_orderable(float f)
{
    unsigned int b = __float_as_uint(f);
    return (b & 0x80000000u) ? ~b : (b | 0x80000000u);
}

#define FENCE asm volatile("" ::: "memory")

// ---------------------------------------------------------------------------
// bf16 256x256 tile, 512 threads (8 waves = 2Mx4N), BK=64, double-buffered
// LDS (128 KB), 4 MFMA clusters/tile with one-cluster-ahead register frag
// prefetch, counted vmcnt, slot-XOR swizzle (conflict-free, r4-verified).
// EPI: 0 = +bias f32 store (col<N masked); 3 = raw f32 partials (K split over
// blockIdx.z). K%64==0; M%256==0; >=3 K-tiles per block; nwg%8==0.
// ---------------------------------------------------------------------------
template<int EPI>
__global__ __launch_bounds__(512, 2) void gemm256(
    const u16* __restrict__ A, const u16* __restrict__ Bt,
    const float* __restrict__ bias, float* __restrict__ Cf,
    int M, int N, int K, int sA, int sB)
{
    extern __shared__ char lds[];

    const int gx = gridDim.x, gy = gridDim.y, gz = gridDim.z;
    const int nwg = gx * gy * gz;
    int flat = (blockIdx.z * gy + blockIdx.y) * gx + blockIdx.x;
    flat = (flat & 7) * (nwg >> 3) + (flat >> 3);
    const int bx = flat % gx;
    const int rem = flat / gx;
    const int by = rem % gy;
    const int bz = rem / gy;
    const int bm = by * 256, bn = bx * 256;

    const int tiles = K >> 6;
    int t0 = 0, t1 = tiles;
    if (EPI == 3) {
        const int qz = tiles / gz, rz = tiles % gz;
        t0 = bz * qz + (bz < rz ? bz : rz);
        t1 = t0 + qz + (bz < rz ? 1 : 0);
        Cf += (size_t)bz * ((size_t)M * N);
    }

    const int tid = threadIdx.x;
    const int wv = tid >> 6, ln = tid & 63;

    const int srow = wv * 8 + (ln >> 3);
    const int scol = (((ln & 7) ^ ((ln >> 3) & 7))) * 8;
    const u16* Asrc = A + (size_t)(bm + srow) * sA + scol;
    const u16* Bsrc = Bt + (size_t)(bn + srow) * sB + scol;
    char* stA = lds + wv * 1024;
    char* stB = lds + 32768 + wv * 1024;

#define STG_A(P, KT, J)                                                       \
    gload_lds16(Asrc + ((size_t)(KT) << 6) + (size_t)(J) * 64 * sA,           \
                stA + (P) * 65536 + (J) * 8192)
#define STG_B(P, KT, J)                                                       \
    gload_lds16(Bsrc + ((size_t)(KT) << 6) + (size_t)(J) * 64 * sB,           \
                stB + (P) * 65536 + (J) * 8192)
#define STAGE_MID(P, KT)                                                      \
    { STG_B(P, KT, 0); STG_B(P, KT, 1); STG_B(P, KT, 2); STG_B(P, KT, 3);     \
      STG_A(P, KT, 0); STG_A(P, KT, 2); }
#define STAGE_END(P, KT)                                                      \
    { STG_A(P, KT, 1); STG_A(P, KT, 3); }

    const int wr = wv >> 2, wc = wv & 3;
    const int fr = ln & 15;
    const int q = ln >> 4;
    const int swz = (fr & 7) << 4;
    const char* Afrag = lds + (size_t)(wr * 128 + fr) * 128;
    const char* Bfrag = lds + 32768 + (size_t)(wc * 64 + fr) * 128;

    v4f acc[8][4];
    #pragma unroll
    for (int m = 0; m < 8; ++m)
        #pragma unroll
        for (int n = 0; n < 4; ++n) acc[m][n] = (v4f)(0.f);

    v8s aP[4], aQ[4], b0[4], b1[4];

#define LD_A(REG, PP, KH, MH)                                                 \
    {                                                                         \
        const char* Ab_ = Afrag + (PP) * 65536;                               \
        const int cb_ = ((KH) * 64 + q * 16) ^ swz;                           \
        _Pragma("unroll")                                                     \
        for (int m = 0; m < 4; ++m)                                           \
            REG[m] = *(const v8s*)(Ab_ + ((MH) * 4 + m) * 2048 + cb_);        \
    }
#define LD_B(REG, PP, KH)                                                     \
    {                                                                         \
        const char* Bb_ = Bfrag + (PP) * 65536;                               \
        const int cb_ = ((KH) * 64 + q * 16) ^ swz;                           \
        _Pragma("unroll")                                                     \
        for (int n = 0; n < 4; ++n)                                           \
            REG[n] = *(const v8s*)(Bb_ + n * 2048 + cb_);                     \
    }
#define MMA(AREG, BREG, MH)                                                   \
    {                                                                         \
        __builtin_amdgcn_s_setprio(1);                                        \
        _Pragma("unroll")                                                     \
        for (int m = 0; m < 4; ++m)                                           \
            _Pragma("unroll")                                                 \
            for (int n = 0; n < 4; ++n)                                       \
                acc[(MH) * 4 + m][n] =                                        \
                    __builtin_amdgcn_mfma_f32_16x16x32_bf16(                  \
                        AREG[m], BREG[n], acc[(MH) * 4 + m][n], 0, 0, 0);     \
        __builtin_amdgcn_s_setprio(0);                                        \
    }

    STAGE_MID(0, t0); STAGE_END(0, t0);
    STAGE_MID(1, t0 + 1); STAGE_END(1, t0 + 1);
    asm volatile("s_waitcnt vmcnt(10)" ::: "memory");
    FENCE; __builtin_amdgcn_s_barrier(); FENCE;
    LD_B(b0, 0, 0); LD_A(aP, 0, 0, 0);

    int cur = 0;
    for (int t = t0; t < t1 - 2; ++t) {
        asm volatile("s_waitcnt vmcnt(8)" ::: "memory");
        FENCE; __builtin_amdgcn_s_barrier(); FENCE;
        LD_B(b1, cur, 1); LD_A(aQ, cur, 1, 0);
        MMA(aP, b0, 0);
        LD_A(aP, cur, 0, 1);
        MMA(aQ, b1, 0);
        FENCE; __builtin_amdgcn_s_barrier(); FENCE;
        STAGE_MID(cur, t + 2);
        LD_A(aQ, cur, 1, 1);
        MMA(aP, b0, 1);
        asm volatile("s_waitcnt vmcnt(8)" ::: "memory");
        LD_B(b0, cur ^ 1, 0); LD_A(aP, cur ^ 1, 0, 0);
        MMA(aQ, b1, 1);
        FENCE; __builtin_amdgcn_s_barrier(); FENCE;
        STAGE_END(cur, t + 2);
        cur ^= 1;
    }
    asm volatile("s_waitcnt vmcnt(8)" ::: "memory");
    FENCE; __builtin_amdgcn_s_barrier(); FENCE;
    LD_B(b1, cur, 1); LD_A(aQ, cur, 1, 0);
    MMA(aP, b0, 0);
    LD_A(aP, cur, 0, 1);
    MMA(aQ, b1, 0);
    LD_A(aQ, cur, 1, 1);
    MMA(aP, b0, 1);
    asm volatile("s_waitcnt vmcnt(2)" ::: "memory");
    LD_B(b0, cur ^ 1, 0); LD_A(aP, cur ^ 1, 0, 0);
    MMA(aQ, b1, 1);
    cur ^= 1;
    asm volatile("s_waitcnt vmcnt(0)" ::: "memory");
    FENCE; __builtin_amdgcn_s_barrier(); FENCE;
    LD_B(b1, cur, 1); LD_A(aQ, cur, 1, 0);
    MMA(aP, b0, 0);
    LD_A(aP, cur, 0, 1);
    MMA(aQ, b1, 0);
    LD_A(aQ, cur, 1, 1);
    MMA(aP, b0, 1);
    MMA(aQ, b1, 1);
#undef MMA
#undef LD_A
#undef LD_B
#undef STAGE_MID
#undef STAGE_END
#undef STG_A
#undef STG_B

    const int rb = q * 4;
    #pragma unroll
    for (int m = 0; m < 8; ++m) {
        const int row = bm + wr * 128 + m * 16 + rb;
        #pragma unroll
        for (int n = 0; n < 4; ++n) {
            const int col = bn + wc * 64 + n * 16 + fr;
            if (EPI == 3) {
                #pragma unroll
                for (int r = 0; r < 4; ++r)
                    Cf[(size_t)(row + r) * N + col] = acc[m][n][r];
            } else if (col < N) {
                const float bv = bias[col];
                #pragma unroll
                for (int r = 0; r < 4; ++r)
                    Cf[(size_t)(row + r) * N + col] = acc[m][n][r] + bv;
            }
        }
    }
}

// ---------------------------------------------------------------------------
// fp8 256x256 tile, BK=128, 2 MFMA clusters/tile, counted vmcnt, swizzle.
// EPI: 3 = raw f32 partials (K split over blockIdx.z); 0 = fscale*acc+bias.
// A,Bt e4m3; sA/sB strides in bytes. K%128==0; >=2 K-tiles; nwg%8==0.
// ---------------------------------------------------------------------------
template<int EPI>
__global__ __launch_bounds__(512, 1) void gemm256f8(
    const u8* __restrict__ A, const u8* __restrict__ Bt,
    const float* __restrict__ bias, float* __restrict__ Cf,
    float fscale, int M, int N, int K, int sA, int sB)
{
    extern __shared__ char lds[];

    const int gx = gridDim.x, gy = gridDim.y, gz = gridDim.z;
    const int nwg = gx * gy * gz;
    int flat = (blockIdx.z * gy + blockIdx.y) * gx + blockIdx.x;
    flat = (flat & 7) * (nwg >> 3) + (flat >> 3);
    const int bx = flat % gx;
    const int rem = flat / gx;
    const int by = rem % gy;
    const int bz = rem / gy;
    const int bm = by * 256, bn = bx * 256;

    const int tiles = K >> 7;
    int t0 = 0, t1 = tiles;
    if (EPI == 3) {
        const int qz = tiles / gz, rz = tiles % gz;
        t0 = bz * qz + (bz < rz ? bz : rz);
        t1 = t0 + qz + (bz < rz ? 1 : 0);
        Cf += (size_t)bz * ((size_t)M * N);
    }

    const int tid = threadIdx.x;
    const int wv = tid >> 6, ln = tid & 63;

    const int srow = wv * 8 + (ln >> 3);
    const int scol = ((ln & 7) ^ ((ln >> 3) & 7)) * 16;
    const u8* Asrc = A + (size_t)(bm + srow) * sA + scol;
    const u8* Bsrc = Bt + (size_t)(bn + srow) * sB + scol;
    char* stA = lds + wv * 1024;
    char* stB = lds + 32768 + wv * 1024;

#define STG_A(P, KT, J)                                                       \
    gload_lds16(Asrc + ((size_t)(KT) << 7) + (size_t)(J) * 64 * sA,           \
                stA + (P) * 65536 + (J) * 8192)
#define STG_B(P, KT, J)                                                       \
    gload_lds16(Bsrc + ((size_t)(KT) << 7) + (size_t)(J) * 64 * sB,           \
                stB + (P) * 65536 + (J) * 8192)
#define STAGE_MID(P, KT)                                                      \
    { STG_B(P, KT, 0); STG_B(P, KT, 1); STG_B(P, KT, 2); STG_B(P, KT, 3);     \
      STG_A(P, KT, 0); STG_A(P, KT, 2); }
#define STAGE_END(P, KT)                                                      \
    { STG_A(P, KT, 1); STG_A(P, KT, 3); }

    const int wr = wv >> 2, wc = wv & 3;
    const int fr = ln & 15, q = ln >> 4;
    const int sw8 = fr & 7;
    const int cbLo = ((2 * q) ^ sw8) << 4;
    const int cbHi = ((2 * q + 1) ^ sw8) << 4;
    const char* Afrag = lds + (size_t)(wr * 128 + fr) * 128;
    const char* Bfrag = lds + 32768 + (size_t)(wc * 64 + fr) * 128;

    v4f acc[8][4];
    #pragma unroll
    for (int m = 0; m < 8; ++m)
        #pragma unroll
        for (int n = 0; n < 4; ++n) acc[m][n] = (v4f)(0.f);

    v8i aP[4], aQ[4], b[4];

#define LD_A(REG, PP, MH)                                                     \
    {                                                                         \
        const char* Ab_ = Afrag + (PP) * 65536;                               \
        _Pragma("unroll")                                                     \
        for (int m = 0; m < 4; ++m) {                                         \
            v4i lo_ = *(const v4i*)(Ab_ + ((MH) * 4 + m) * 2048 + cbLo);      \
            v4i hi_ = *(const v4i*)(Ab_ + ((MH) * 4 + m) * 2048 + cbHi);      \
            v8i f_;                                                           \
            _Pragma("unroll")                                                 \
            for (int z = 0; z < 4; ++z) { f_[z] = lo_[z]; f_[z + 4] = hi_[z]; } \
            REG[m] = f_;                                                      \
        }                                                                     \
    }
#define LD_B(PP)                                                              \
    {                                                                         \
        const char* Bb_ = Bfrag + (PP) * 65536;                               \
        _Pragma("unroll")                                                     \
        for (int n = 0; n < 4; ++n) {                                         \
            v4i lo_ = *(const v4i*)(Bb_ + n * 2048 + cbLo);                   \
            v4i hi_ = *(const v4i*)(Bb_ + n * 2048 + cbHi);                   \
            v8i f_;                                                           \
            _Pragma("unroll")                                                 \
            for (int z = 0; z < 4; ++z) { f_[z] = lo_[z]; f_[z + 4] = hi_[z]; } \
            b[n] = f_;                                                        \
        }                                                                     \
    }
#define MMA(AR, MH)                                                           \
    {                                                                         \
        __builtin_amdgcn_s_setprio(1);                                        \
        _Pragma("unroll")                                                     \
        for (int m = 0; m < 4; ++m)                                           \
            _Pragma("unroll")                                                 \
            for (int n = 0; n < 4; ++n)                                       \
                acc[(MH) * 4 + m][n] =                                        \
                    __builtin_amdgcn_mfma_scale_f32_16x16x128_f8f6f4(         \
                        AR[m], b[n], acc[(MH) * 4 + m][n],                    \
                        0, 0, 0, 0x7F7F7F7F, 0, 0x7F7F7F7F);                  \
        __builtin_amdgcn_s_setprio(0);                                        \
    }

    STAGE_MID(0, t0); STAGE_END(0, t0);
    STAGE_MID(1, t0 + 1); STAGE_END(1, t0 + 1);
    asm volatile("s_waitcnt vmcnt(10)" ::: "memory");
    FENCE; __builtin_amdgcn_s_barrier(); FENCE;
    LD_A(aP, 0, 0);

    int cur = 0;
    for (int t = t0; t < t1 - 2; ++t) {
        asm volatile("s_waitcnt vmcnt(8)" ::: "memory");
        FENCE; __builtin_amdgcn_s_barrier(); FENCE;
        LD_B(cur); LD_A(aQ, cur, 1);
        MMA(aP, 0);
        FENCE; __builtin_amdgcn_s_barrier(); FENCE;
        STAGE_MID(cur, t + 2);
        asm volatile("s_waitcnt vmcnt(8)" ::: "memory");
        MMA(aQ, 1);
        FENCE; __builtin_amdgcn_s_barrier(); FENCE;
        LD_A(aP, cur ^ 1, 0);
        STAGE_END(cur, t + 2);
        cur ^= 1;
    }
    asm volatile("s_waitcnt vmcnt(8)" ::: "memory");
    FENCE; __builtin_amdgcn_s_barrier(); FENCE;
    LD_B(cur); LD_A(aQ, cur, 1);
    MMA(aP, 0);
    MMA(aQ, 1);
    cur ^= 1;
    asm volatile("s_waitcnt vmcnt(0)" ::: "memory");
    FENCE; __builtin_amdgcn_s_barrier(); FENCE;
    LD_B(cur); LD_A(aP, cur, 0); LD_A(aQ, cur, 1);
    MMA(aP, 0);
    MMA(aQ, 1);
#undef MMA
#undef LD_A
#undef LD_B
#undef STAGE_MID
#undef STAGE_END
#undef STG_A
#undef STG_B

    const int rb = q * 4;
    #pragma unroll
    for (int m = 0; m < 8; ++m) {
        const int row = bm + wr * 128 + m * 16 + rb;
        #pragma unroll
        for (int n = 0; n < 4; ++n) {
            const int col = bn + wc * 64 + n * 16 + fr;
            if (EPI == 3) {
                #pragma unroll
                for (int r = 0; r < 4; ++r)
                    Cf[(size_t)(row + r) * N + col] = acc[m][n][r];
            } else if (col < N) {
                const float bv = bias[col];
                #pragma unroll
                for (int r = 0; r < 4; ++r)
                    Cf[(size_t)(row + r) * N + col] =
                        fmaf(acc[m][n][r], fscale, bv);
            }
        }
    }
}

// ---------------------------------------------------------------------------
// 128x128 bf16 kernel: small GEMMs + fused-argmin VQ.
// EPI: 0 = +bias, 1 = tanh(+bias), 2 = VQ argmin. WB/WF: bf16/f32 writes.
// ---------------------------------------------------------------------------
template<int EPI, int WB, int WF>
__global__ __launch_bounds__(256, 2) void mfma_gemm(
    const u16* __restrict__ A, const u16* __restrict__ Bt,
    const float* __restrict__ bias, float* __restrict__ Cf,
    u16* __restrict__ Cb, u64* __restrict__ packed, int M, int N, int K)
{
    __shared__ u16 As[128 * 32];
    __shared__ u16 Bs[128 * 32];
    const int tid = threadIdx.x;
    const int wv = tid >> 6;
    const int ln = tid & 63;
    const int bm = blockIdx.y * 128;
    const int bn = blockIdx.x * 128;

    const int srow = wv * 32 + (ln >> 2);
    const int skel = (ln & 3) * 8;
    const u16* Ap0 = A + (size_t)(bm + srow) * K + skel;
    const u16* Ap1 = Ap0 + (size_t)16 * K;
    const u16* Bp0 = Bt + (size_t)(bn + srow) * K + skel;
    const u16* Bp1 = Bp0 + (size_t)16 * K;
    u16* lA0 = As + wv * 1024;
    u16* lA1 = lA0 + 512;
    u16* lB0 = Bs + wv * 1024;
    u16* lB1 = lB0 + 512;

    const int wr = wv >> 1, wc = wv & 1;
    const int fr = ln & 15;
    const int kg = (ln >> 4) * 8;
    const u16* Afp = As + (wr * 64 + fr) * 32 + kg;
    const u16* Bfp = Bs + (wc * 64 + fr) * 32 + kg;

    v4f acc[4][4];
    #pragma unroll
    for (int m = 0; m < 4; ++m)
        #pragma unroll
        for (int n = 0; n < 4; ++n) acc[m][n] = (v4f)(0.f);

    for (int k0 = 0; k0 < K; k0 += 32) {
        __syncthreads();
        gload_lds16(Ap0 + k0, lA0);
        gload_lds16(Ap1 + k0, lA1);
        gload_lds16(Bp0 + k0, lB0);
        gload_lds16(Bp1 + k0, lB1);
        __syncthreads();
        v8s a[4], b[4];
        #pragma unroll
        for (int m = 0; m < 4; ++m) a[m] = *(const v8s*)(Afp + m * 512);
        #pragma unroll
        for (int n = 0; n < 4; ++n) b[n] = *(const v8s*)(Bfp + n * 512);
        #pragma unroll
        for (int m = 0; m < 4; ++m)
            #pragma unroll
            for (int n = 0; n < 4; ++n)
                acc[m][n] = __builtin_amdgcn_mfma_f32_16x16x32_bf16(
                    a[m], b[n], acc[m][n], 0, 0, 0);
    }

    const int rb = (ln >> 4) * 4;

    if constexpr (EPI == 2) {
        __shared__ u64 smin[128];
        if (tid < 128) smin[tid] = ~0ull;
        __syncthreads();
        #pragma unroll
        for (int m = 0; m < 4; ++m) {
            #pragma unroll
            for (int r = 0; r < 4; ++r) {
                u64 best = ~0ull;
                #pragma unroll
                for (int n = 0; n < 4; ++n) {
                    const int col = bn + wc * 64 + n * 16 + fr;
                    const float s = fmaf(-2.f, acc[m][n][r], bias[col]);
                    const u64 pv =
                        ((u64)float_orderable(s) << 32) | (unsigned)col;
                    best = pv < best ? pv : best;
                }
                #pragma unroll
                for (int msk = 1; msk <= 8; msk <<= 1) {
                    const u64 o = __shfl_xor(best, msk);
                    best = o < best ? o : best;
                }
                if (fr == 0) atomicMin(&smin[wr * 64 + m * 16 + rb + r], best);
            }
        }
        __syncthreads();
        if (tid < 128) atomicMin(&packed[bm + tid], smin[tid]);
    } else {
        #pragma unroll
        for (int m = 0; m < 4; ++m) {
            const int row = bm + wr * 64 + m * 16 + rb;
            #pragma unroll
            for (int n = 0; n < 4; ++n) {
                const int col = bn + wc * 64 + n * 16 + fr;
                if (col < N) {
                    const float bv = bias[col];
                    #pragma unroll
                    for (int r = 0; r < 4; ++r) {
                        float v = acc[m][n][r] + bv;
                        if (EPI == 1) v = tanhf(v);
                        if (WF) Cf[(size_t)(row + r) * N + col] = v;
                        if (WB) Cb[(size_t)(row + r) * N + col] = f2b(v);
                    }
                }
            }
        }
    }
}

// out[i] = bf16(tanh((sum_c P_c) * fs + bias)), 8 elems/thread, NC chunks.
template<int NC>
__global__ __launch_bounds__(256) void reduce_tanh(
    const float* __restrict__ P, const float* __restrict__ bias,
    u16* __restrict__ out, long n8, int N, size_t cs, float fs)
{
    const long stride = (long)gridDim.x * 256;
    for (long i = (long)blockIdx.x * 256 + threadIdx.x; i < n8; i += stride) {
        const size_t e0 = (size_t)i * 8;
        const int col = (int)(e0 & (size_t)(N - 1));
        float4 s0 = *(const float4*)(P + e0);
        float4 s1 = *(const float4*)(P + e0 + 4);
        #pragma unroll
        for (int c = 1; c < NC; ++c) {
            const float4 a = *(const float4*)(P + c * cs + e0);
            const float4 b = *(const float4*)(P + c * cs + e0 + 4);
            s0.x += a.x; s0.y += a.y; s0.z += a.z; s0.w += a.w;
            s1.x += b.x; s1.y += b.y; s1.z += b.z; s1.w += b.w;
        }
        const float4 bv0 = *(const float4*)(bias + col);
        const float4 bv1 = *(const float4*)(bias + col + 4);
        v8s o;
        o[0] = (short)f2b(tanhf(fmaf(s0.x, fs, bv0.x)));
        o[1] = (short)f2b(tanhf(fmaf(s0.y, fs, bv0.y)));
        o[2] = (short)f2b(tanhf(fmaf(s0.z, fs, bv0.z)));
        o[3] = (short)f2b(tanhf(fmaf(s0.w, fs, bv0.w)));
        o[4] = (short)f2b(tanhf(fmaf(s1.x, fs, bv1.x)));
        o[5] = (short)f2b(tanhf(fmaf(s1.y, fs, bv1.y)));
        o[6] = (short)f2b(tanhf(fmaf(s1.z, fs, bv1.z)));
        o[7] = (short)f2b(tanhf(fmaf(s1.w, fs, bv1.w)));
        *(v8s*)(out + e0) = o;
    }
}

// x [4096][20000] f32 -> xb [4096][20096] e4m3, zero-padded. 1 block per row.
__global__ __launch_bounds__(256) void conv_pad_x_f8(
    const float* __restrict__ in, u8* __restrict__ out)
{
    const int row = blockIdx.x;
    const float* src = in + (size_t)row * 20000;
    u8* dst = out + (size_t)row * 20096;
    for (int j = threadIdx.x; j < 2512; j += 256) {
        u64 o = 0;
        if (j < 2500) {
            const float4 a = *(const float4*)(src + j * 8);
            const float4 b = *(const float4*)(src + j * 8 + 4);
            o |= (u64)f2e4m3(a.x) << 0;  o |= (u64)f2e4m3(a.y) << 8;
            o |= (u64)f2e4m3(a.z) << 16; o |= (u64)f2e4m3(a.w) << 24;
            o |= (u64)f2e4m3(b.x) << 32; o |= (u64)f2e4m3(b.y) << 40;
            o |= (u64)f2e4m3(b.z) << 48; o |= (u64)f2e4m3(b.w) << 56;
        }
        *(u64*)(dst + j * 8) = o;
    }
}

// f32 -> bf16 elementwise, 8/thread. n8 = n/8.
__global__ __launch_bounds__(256) void conv_bf16(
    const float* __restrict__ in, u16* __restrict__ out, long n8)
{
    const long stride = (long)gridDim.x * 256;
    for (long i = (long)blockIdx.x * 256 + threadIdx.x; i < n8; i += stride) {
        const float4 a = ((const float4*)in)[i * 2];
        const float4 b = ((const float4*)in)[i * 2 + 1];
        v8s o;
        o[0] = (short)f2b(a.x); o[1] = (short)f2b(a.y);
        o[2] = (short)f2b(a.z); o[3] = (short)f2b(a.w);
        o[4] = (short)f2b(b.x); o[5] = (short)f2b(b.y);
        o[6] = (short)f2b(b.z); o[7] = (short)f2b(b.w);
        *(v8s*)(out + i * 8) = o;
    }
}

// W[K][N] f32 -> Wt[N][Kp] bf16, rows k>=K zero-filled. block (32,8).
__global__ __launch_bounds__(256) void trans_bf16p(
    const float* __restrict__ W, u16* __restrict__ Wt, int K, int N, int Kp)
{
    __shared__ float t[32][33];
    const int tx = threadIdx.x, ty = threadIdx.y;
    const int n0 = blockIdx.x * 32, k0 = blockIdx.y * 32;
    #pragma unroll
    for (int i = 0; i < 32; i += 8) {
        const int n = n0 + tx;
        const int k = k0 + ty + i;
        t[ty + i][tx] = (n < N && k < K) ? W[(size_t)k * N + n] : 0.f;
    }
    __syncthreads();
    #pragma unroll
    for (int i = 0; i < 32; i += 8) {
        const int n = n0 + ty + i;
        if (n < N) Wt[(size_t)n * Kp + k0 + tx] = f2b(t[tx][ty + i]);
    }
}

// W[K][N] f32 -> Wt[N][Kp] e4m3 of (w*scale), rows k>=K zero-filled.
__global__ __launch_bounds__(256) void trans_f8p(
    const float* __restrict__ W, u8* __restrict__ Wt, int K, int N, int Kp,
    float scale)
{
    __shared__ float t[32][33];
    const int tx = threadIdx.x, ty = threadIdx.y;
    const int n0 = blockIdx.x * 32, k0 = blockIdx.y * 32;
    #pragma unroll
    for (int i = 0; i < 32; i += 8) {
        const int n = n0 + tx;
        const int k = k0 + ty + i;
        t[ty + i][tx] = (n < N && k < K) ? W[(size_t)k * N + n] * scale : 0.f;
    }
    __syncthreads();
    #pragma unroll
    for (int i = 0; i < 32; i += 8) {
        const int n = n0 + ty + i;
        if (n < N) Wt[(size_t)n * Kp + k0 + tx] = f2e4m3(t[tx][ty + i]);
    }
}

// cnorm[k] = ||codebook[k]||^2 (f32), one wave per row.
__global__ __launch_bounds__(64) void cnorm_k(
    const float* __restrict__ CB, float* __restrict__ cn)
{
    const float* row = CB + (size_t)blockIdx.x * 512;
    float s = 0.f;
    #pragma unroll
    for (int u = 0; u < 8; ++u) {
        const float v = row[threadIdx.x + 64 * u];
        s = fmaf(v, v, s);
    }
    #pragma unroll
    for (int m = 32; m; m >>= 1) s += __shfl_down(s, m);
    if (threadIdx.x == 0) cn[blockIdx.x] = s;
}

__global__ void init_packed(u64* __restrict__ p)
{
    p[blockIdx.x * 256 + threadIdx.x] = ~0ull;
}

// gather q rows -> qout (f32) + qb (bf16); block partials of sum((q-z)^2).
__global__ __launch_bounds__(256) void quant_loss(
    const u64* __restrict__ packed, const float* __restrict__ CB,
    const float* __restrict__ Z, float* __restrict__ qout,
    u16* __restrict__ qb, double* __restrict__ partials)
{
    const int gid = blockIdx.x * 256 + threadIdx.x;
    const int i = gid >> 7;
    const int j = (gid & 127) << 2;
    const int k = (int)(packed[i] & 0xffffffffull);
    const float4 c = *(const float4*)(CB + (size_t)k * 512 + j);
    const float4 z = *(const float4*)(Z + (size_t)i * 512 + j);
    const size_t o = (size_t)i * 512 + j;
    qout[o + 0] = c.x; qout[o + 1] = c.y; qout[o + 2] = c.z; qout[o + 3] = c.w;
    qb[o + 0] = f2b(c.x); qb[o + 1] = f2b(c.y);
    qb[o + 2] = f2b(c.z); qb[o + 3] = f2b(c.w);
    const float d0 = c.x - z.x, d1 = c.y - z.y, d2 = c.z - z.z, d3 = c.w - z.w;
    float local = d0 * d0 + d1 * d1 + d2 * d2 + d3 * d3;
    #pragma unroll
    for (int m = 32; m; m >>= 1) local += __shfl_down(local, m);
    __shared__ float wsum[4];
    if ((threadIdx.x & 63) == 0) wsum[threadIdx.x >> 6] = local;
    __syncthreads();
    if (threadIdx.x == 0)
        partials[blockIdx.x] = (double)wsum[0] + (double)wsum[1] +
                               (double)wsum[2] + (double)wsum[3];
}

__global__ __launch_bounds__(256) void loss_final(
    const double* __restrict__ partials, float* __restrict__ out)
{
    double s = 0.0;
    for (int u = threadIdx.x; u < 2048; u += 256) s += partials[u];
    #pragma unroll
    for (int m = 32; m; m >>= 1) s += __shfl_down(s, m);
    __shared__ double ws[4];
    if ((threadIdx.x & 63) == 0) ws[threadIdx.x >> 6] = s;
    __syncthreads();
    if (threadIdx.x == 0)
        out[0] = (float)(1.25 * (ws[0] + ws[1] + ws[2] + ws[3]) / 2097152.0);
}

extern "C" void kernel_launch(void* const* d_in, const int* in_sizes, int n_in,
                              void* d_out, int out_size, void* d_ws, size_t ws_size,
                              hipStream_t stream)
{
    const float* x  = (const float*)d_in[0];
    const float* W1 = (const float*)d_in[1];
    const float* b1 = (const float*)d_in[2];
    const float* W2 = (const float*)d_in[3];
    const float* b2 = (const float*)d_in[4];
    const float* W3 = (const float*)d_in[5];
    const float* b3 = (const float*)d_in[6];
    const float* CB = (const float*)d_in[7];
    const float* W4 = (const float*)d_in[8];
    const float* b4 = (const float*)d_in[9];
    const float* W5 = (const float*)d_in[10];
    const float* b5 = (const float*)d_in[11];
    const float* W6 = (const float*)d_in[12];
    const float* b6 = (const float*)d_in[13];

    float* out  = (float*)d_out;
    float* xrec = out + 1;
    float* qout = out + 1 + (size_t)4096 * 20000;

    // scratch inside d_out's x_recon region (dead until final GEMM):
    u8*    XB8   = (u8*)((char*)d_out + 16);                 // [4096][20096] e4m3
    float* PART1 = (float*)((char*)d_out + 16 + 82313216);   // 2x[4096][2048] f32

    char* ws = (char*)d_ws;
    u8*  W1T8 = (u8*)(ws + 0);            // [2048][20096] e4m3 (dead after GEMM1)
    u16* WT6  = (u16*)(ws + 0);           // [20224][2048] bf16 (after GEMM1)
    u16* WT2  = (u16*)(ws + 82837504);    // [1024][2048] bf16
    u16* WT3  = (u16*)(ws + 87031808);    // [512][1024]
    u16* CBB  = (u16*)(ws + 88080384);    // [8192][512]
    u16* WT4  = (u16*)(ws + 96468992);    // [1024][512]
    u16* WT5  = (u16*)(ws + 97517568);    // [2048][1024]
    u16* ACT1 = (u16*)(ws + 101711872);   // [4096][2048] z1, later h2
    u16* ACT2 = (u16*)(ws + 118489088);   // [4096][1024] z2, later h1
    float* Z3F = (float*)(ws + 126877696); // [4096][512]
    u16* Z3B  = (u16*)(ws + 135266304);   // [4096][512]
    u16* QB   = (u16*)(ws + 139460608);   // [4096][512]
    float* CN = (float*)(ws + 143654912);
    u64* PACKED = (u64*)(ws + 143687680);
    double* PART = (double*)(ws + 143720448);

    const dim3 blk(256);

    // ---- precompute ----
    conv_pad_x_f8<<<dim3(4096), blk, 0, stream>>>(x, XB8);
    conv_bf16<<<dim3(2048), blk, 0, stream>>>(CB, CBB, 524288L);
    trans_f8p<<<dim3(64, 628), dim3(32, 8), 0, stream>>>(
        W1, W1T8, 20000, 2048, 20096, 4096.f);          // W1 x 2^12
    trans_bf16p<<<dim3(32, 64),  dim3(32, 8), 0, stream>>>(W2, WT2, 2048, 1024, 2048);
    trans_bf16p<<<dim3(16, 32),  dim3(32, 8), 0, stream>>>(W3, WT3, 1024, 512, 1024);
    trans_bf16p<<<dim3(32, 16),  dim3(32, 8), 0, stream>>>(W4, WT4, 512, 1024, 512);
    trans_bf16p<<<dim3(64, 32),  dim3(32, 8), 0, stream>>>(W5, WT5, 1024, 2048, 1024);
    cnorm_k<<<dim3(8192), dim3(64), 0, stream>>>(CB, CN);
    init_packed<<<dim3(16), blk, 0, stream>>>(PACKED);

    // ---- encoder ----
    // GEMM1: fp8 256^2, split-K 2 (256 blocks); 2^-12 compensation in reduce
    gemm256f8<3><<<dim3(8, 16, 2), dim3(512), 131072, stream>>>(
        XB8, W1T8, nullptr, PART1, 1.f, 4096, 2048, 20096, 20096, 20096);
    reduce_tanh<2><<<dim3(4096), blk, 0, stream>>>(
        PART1, b1, ACT1, 1048576L, 2048, (size_t)4096 * 2048, 1.f / 4096.f);
    // W1T8 dead; transpose W6 (bf16) into the same arena
    trans_bf16p<<<dim3(625, 64), dim3(32, 8), 0, stream>>>(W6, WT6, 2048, 20000, 2048);
    mfma_gemm<1, 1, 0><<<dim3(8, 32), blk, 0, stream>>>(
        ACT1, WT2, b2, nullptr, ACT2, nullptr, 4096, 1024, 2048);
    mfma_gemm<1, 1, 1><<<dim3(4, 32), blk, 0, stream>>>(
        ACT2, WT3, b3, Z3F, Z3B, nullptr, 4096, 512, 1024);

    // ---- VQ: 128^2 score GEMM with fused argmin, then gather + loss ----
    mfma_gemm<2, 0, 0><<<dim3(64, 32), blk, 0, stream>>>(
        Z3B, CBB, CN, nullptr, nullptr, PACKED, 4096, 8192, 512);
    quant_loss<<<dim3(2048), blk, 0, stream>>>(PACKED, CB, Z3F, qout, QB, PART);
    loss_final<<<dim3(1), blk, 0, stream>>>(PART, out);

    // ---- decoder ----
    mfma_gemm<1, 1, 0><<<dim3(8, 32), blk, 0, stream>>>(
        QB, WT4, b4, nullptr, ACT2, nullptr, 4096, 1024, 512);
    mfma_gemm<1, 1, 0><<<dim3(16, 32), blk, 0, stream>>>(
        ACT2, WT5, b5, nullptr, ACT1, nullptr, 4096, 2048, 1024);
    // GEMM6: bf16 256^2 (reverted), grid 79x16 = 1264 blocks
    gemm256<0><<<dim3(79, 16), dim3(512), 131072, stream>>>(
        ACT1, WT6, b6, xrec, 4096, 20000, 2048, 2048, 2048);
}

// Round 9
// 1015.935 us; speedup vs baseline: 1.2131x; 1.0284x over previous
//
#include <hip/hip_runtime.h>
#include <hip/hip_bf16.h>
#include <math.h>

// ---------------------------------------------------------------------------
// VQ-VAE forward. B=4096, G=20000, dims 2048/1024/512, K=8192 codes.
// Round 9: GEMM6 block-order remap — per-XCD region 20bx x 8by (grid padded
// to 80x16, bx=79 dead), traversed in 5bx x 8by supertiles, bx-fastest inner.
// Shrinks the concurrent panel window from 18.9 MB (2by x 16bx) to ~13.7 MB
// -> predicted FETCH 672 -> ~450-500 MB on the L2-miss-bound GEMM6.
// GEMM1 stays MX-fp8 split-K2; K-loop/swizzle/epilogue untouched (r4-r8
// verified). Small GEMMs + fused-argmin VQ on the 128^2 bf16 kernel.
// ---------------------------------------------------------------------------

typedef short v8s __attribute__((ext_vector_type(8)));
typedef float v4f __attribute__((ext_vector_type(4)));
typedef int   v8i __attribute__((ext_vector_type(8)));
typedef int   v4i __attribute__((ext_vector_type(4)));
typedef unsigned short u16;
typedef unsigned char  u8;
typedef unsigned long long u64;

typedef const unsigned int __attribute__((address_space(1)))* as1p;
typedef unsigned int __attribute__((address_space(3)))* as3p;

__device__ __forceinline__ void gload_lds16(const void* g, void* l) {
    __builtin_amdgcn_global_load_lds((as1p)g, (as3p)l, 16, 0, 0);
}

__device__ __forceinline__ u16 f2b(float f) {
    return __builtin_bit_cast(u16, __float2bfloat16(f));
}

// f32 -> OCP e4m3fn, RNE on normals, FTZ below 2^-6, clamp to 448
__device__ __forceinline__ u8 f2e4m3(float f) {
    unsigned u = __float_as_uint(f);
    unsigned s = (u >> 24) & 0x80u;
    unsigned a = u & 0x7FFFFFFFu;
    if (a < 0x3C800000u) return (u8)s;
    if (a > 0x43E00000u) a = 0x43E00000u;
    a += ((a >> 20) & 1u) + 0x7FFFFu;
    if (a > 0x43E00000u) a = 0x43E00000u;
    unsigned e = (a >> 23) - 120u;
    unsigned m = (a >> 20) & 7u;
    return (u8)(s | (e << 3) | m);
}

__device__ __forceinline__ unsigned int float_orderable(float f)
{
    unsigned int b = __float_as_uint(f);
    return (b & 0x80000000u) ? ~b : (b | 0x80000000u);
}

#define FENCE asm volatile("" ::: "memory")

// ---------------------------------------------------------------------------
// bf16 256x256 tile, 512 threads (8 waves = 2Mx4N), BK=64, double-buffered
// LDS (128 KB), 4 MFMA clusters/tile with one-cluster-ahead register frag
// prefetch, counted vmcnt, slot-XOR swizzle (conflict-free, r4-verified).
// EPI 0 (+bias f32 store): GEMM6-specific supertile block order — grid MUST
// be 80x16, bx=79 dead. Per-XCD (o&7) region 20bx x 8by; supertiles 5bx x
// 8by; bx fastest. EPI 3 (raw f32 partials, K split over blockIdx.z): linear
// XCD swizzle (nwg%8==0). K%64==0; M%256==0; >=3 K-tiles per block.
// ---------------------------------------------------------------------------
template<int EPI>
__global__ __launch_bounds__(512, 2) void gemm256(
    const u16* __restrict__ A, const u16* __restrict__ Bt,
    const float* __restrict__ bias, float* __restrict__ Cf,
    int M, int N, int K, int sA, int sB)
{
    extern __shared__ char lds[];

    int bx, by, bz = 0;
    if constexpr (EPI == 0) {
        // supertiled region map (assumes XCD = flat_id & 7, grid 80x16)
        const int o = blockIdx.y * gridDim.x + blockIdx.x;
        const int k = o & 7, c = o >> 3;          // c in [0,160)
        const int st = c / 40, wi = c % 40;       // 4 supertiles of 5x8
        bx = (k & 3) * 20 + st * 5 + wi % 5;
        by = (k >> 2) * 8 + wi / 5;
        if (bx >= 79) return;                     // dead pad column
    } else {
        const int gx = gridDim.x, gy = gridDim.y, gz = gridDim.z;
        const int nwg = gx * gy * gz;
        int flat = (blockIdx.z * gy + blockIdx.y) * gx + blockIdx.x;
        flat = (flat & 7) * (nwg >> 3) + (flat >> 3);
        bx = flat % gx;
        const int rem = flat / gx;
        by = rem % gy;
        bz = rem / gy;
    }
    const int bm = by * 256, bn = bx * 256;

    const int tiles = K >> 6;
    int t0 = 0, t1 = tiles;
    if (EPI == 3) {
        const int gz = gridDim.z;
        const int qz = tiles / gz, rz = tiles % gz;
        t0 = bz * qz + (bz < rz ? bz : rz);
        t1 = t0 + qz + (bz < rz ? 1 : 0);
        Cf += (size_t)bz * ((size_t)M * N);
    }

    const int tid = threadIdx.x;
    const int wv = tid >> 6, ln = tid & 63;

    const int srow = wv * 8 + (ln >> 3);
    const int scol = (((ln & 7) ^ ((ln >> 3) & 7))) * 8;
    const u16* Asrc = A + (size_t)(bm + srow) * sA + scol;
    const u16* Bsrc = Bt + (size_t)(bn + srow) * sB + scol;
    char* stA = lds + wv * 1024;
    char* stB = lds + 32768 + wv * 1024;

#define STG_A(P, KT, J)                                                       \
    gload_lds16(Asrc + ((size_t)(KT) << 6) + (size_t)(J) * 64 * sA,           \
                stA + (P) * 65536 + (J) * 8192)
#define STG_B(P, KT, J)                                                       \
    gload_lds16(Bsrc + ((size_t)(KT) << 6) + (size_t)(J) * 64 * sB,           \
                stB + (P) * 65536 + (J) * 8192)
#define STAGE_MID(P, KT)                                                      \
    { STG_B(P, KT, 0); STG_B(P, KT, 1); STG_B(P, KT, 2); STG_B(P, KT, 3);     \
      STG_A(P, KT, 0); STG_A(P, KT, 2); }
#define STAGE_END(P, KT)                                                      \
    { STG_A(P, KT, 1); STG_A(P, KT, 3); }

    const int wr = wv >> 2, wc = wv & 3;
    const int fr = ln & 15;
    const int q = ln >> 4;
    const int swz = (fr & 7) << 4;
    const char* Afrag = lds + (size_t)(wr * 128 + fr) * 128;
    const char* Bfrag = lds + 32768 + (size_t)(wc * 64 + fr) * 128;

    v4f acc[8][4];
    #pragma unroll
    for (int m = 0; m < 8; ++m)
        #pragma unroll
        for (int n = 0; n < 4; ++n) acc[m][n] = (v4f)(0.f);

    v8s aP[4], aQ[4], b0[4], b1[4];

#define LD_A(REG, PP, KH, MH)                                                 \
    {                                                                         \
        const char* Ab_ = Afrag + (PP) * 65536;                               \
        const int cb_ = ((KH) * 64 + q * 16) ^ swz;                           \
        _Pragma("unroll")                                                     \
        for (int m = 0; m < 4; ++m)                                           \
            REG[m] = *(const v8s*)(Ab_ + ((MH) * 4 + m) * 2048 + cb_);        \
    }
#define LD_B(REG, PP, KH)                                                     \
    {                                                                         \
        const char* Bb_ = Bfrag + (PP) * 65536;                               \
        const int cb_ = ((KH) * 64 + q * 16) ^ swz;                           \
        _Pragma("unroll")                                                     \
        for (int n = 0; n < 4; ++n)                                           \
            REG[n] = *(const v8s*)(Bb_ + n * 2048 + cb_);                     \
    }
#define MMA(AREG, BREG, MH)                                                   \
    {                                                                         \
        __builtin_amdgcn_s_setprio(1);                                        \
        _Pragma("unroll")                                                     \
        for (int m = 0; m < 4; ++m)                                           \
            _Pragma("unroll")                                                 \
            for (int n = 0; n < 4; ++n)                                       \
                acc[(MH) * 4 + m][n] =                                        \
                    __builtin_amdgcn_mfma_f32_16x16x32_bf16(                  \
                        AREG[m], BREG[n], acc[(MH) * 4 + m][n], 0, 0, 0);     \
        __builtin_amdgcn_s_setprio(0);                                        \
    }

    STAGE_MID(0, t0); STAGE_END(0, t0);
    STAGE_MID(1, t0 + 1); STAGE_END(1, t0 + 1);
    asm volatile("s_waitcnt vmcnt(10)" ::: "memory");
    FENCE; __builtin_amdgcn_s_barrier(); FENCE;
    LD_B(b0, 0, 0); LD_A(aP, 0, 0, 0);

    int cur = 0;
    for (int t = t0; t < t1 - 2; ++t) {
        asm volatile("s_waitcnt vmcnt(8)" ::: "memory");
        FENCE; __builtin_amdgcn_s_barrier(); FENCE;
        LD_B(b1, cur, 1); LD_A(aQ, cur, 1, 0);
        MMA(aP, b0, 0);
        LD_A(aP, cur, 0, 1);
        MMA(aQ, b1, 0);
        FENCE; __builtin_amdgcn_s_barrier(); FENCE;
        STAGE_MID(cur, t + 2);
        LD_A(aQ, cur, 1, 1);
        MMA(aP, b0, 1);
        asm volatile("s_waitcnt vmcnt(8)" ::: "memory");
        LD_B(b0, cur ^ 1, 0); LD_A(aP, cur ^ 1, 0, 0);
        MMA(aQ, b1, 1);
        FENCE; __builtin_amdgcn_s_barrier(); FENCE;
        STAGE_END(cur, t + 2);
        cur ^= 1;
    }
    asm volatile("s_waitcnt vmcnt(8)" ::: "memory");
    FENCE; __builtin_amdgcn_s_barrier(); FENCE;
    LD_B(b1, cur, 1); LD_A(aQ, cur, 1, 0);
    MMA(aP, b0, 0);
    LD_A(aP, cur, 0, 1);
    MMA(aQ, b1, 0);
    LD_A(aQ, cur, 1, 1);
    MMA(aP, b0, 1);
    asm volatile("s_waitcnt vmcnt(2)" ::: "memory");
    LD_B(b0, cur ^ 1, 0); LD_A(aP, cur ^ 1, 0, 0);
    MMA(aQ, b1, 1);
    cur ^= 1;
    asm volatile("s_waitcnt vmcnt(0)" ::: "memory");
    FENCE; __builtin_amdgcn_s_barrier(); FENCE;
    LD_B(b1, cur, 1); LD_A(aQ, cur, 1, 0);
    MMA(aP, b0, 0);
    LD_A(aP, cur, 0, 1);
    MMA(aQ, b1, 0);
    LD_A(aQ, cur, 1, 1);
    MMA(aP, b0, 1);
    MMA(aQ, b1, 1);
#undef MMA
#undef LD_A
#undef LD_B
#undef STAGE_MID
#undef STAGE_END
#undef STG_A
#undef STG_B

    const int rb = q * 4;
    #pragma unroll
    for (int m = 0; m < 8; ++m) {
        const int row = bm + wr * 128 + m * 16 + rb;
        #pragma unroll
        for (int n = 0; n < 4; ++n) {
            const int col = bn + wc * 64 + n * 16 + fr;
            if (EPI == 3) {
                #pragma unroll
                for (int r = 0; r < 4; ++r)
                    Cf[(size_t)(row + r) * N + col] = acc[m][n][r];
            } else if (col < N) {
                const float bv = bias[col];
                #pragma unroll
                for (int r = 0; r < 4; ++r)
                    Cf[(size_t)(row + r) * N + col] = acc[m][n][r] + bv;
            }
        }
    }
}

// ---------------------------------------------------------------------------
// fp8 256x256 tile, BK=128, 2 MFMA clusters/tile, counted vmcnt, swizzle.
// EPI: 3 = raw f32 partials (K split over blockIdx.z); 0 = fscale*acc+bias.
// A,Bt e4m3; sA/sB strides in bytes. K%128==0; >=2 K-tiles; nwg%8==0.
// ---------------------------------------------------------------------------
template<int EPI>
__global__ __launch_bounds__(512, 1) void gemm256f8(
    const u8* __restrict__ A, const u8* __restrict__ Bt,
    const float* __restrict__ bias, float* __restrict__ Cf,
    float fscale, int M, int N, int K, int sA, int sB)
{
    extern __shared__ char lds[];

    const int gx = gridDim.x, gy = gridDim.y, gz = gridDim.z;
    const int nwg = gx * gy * gz;
    int flat = (blockIdx.z * gy + blockIdx.y) * gx + blockIdx.x;
    flat = (flat & 7) * (nwg >> 3) + (flat >> 3);
    const int bx = flat % gx;
    const int rem = flat / gx;
    const int by = rem % gy;
    const int bz = rem / gy;
    const int bm = by * 256, bn = bx * 256;

    const int tiles = K >> 7;
    int t0 = 0, t1 = tiles;
    if (EPI == 3) {
        const int qz = tiles / gz, rz = tiles % gz;
        t0 = bz * qz + (bz < rz ? bz : rz);
        t1 = t0 + qz + (bz < rz ? 1 : 0);
        Cf += (size_t)bz * ((size_t)M * N);
    }

    const int tid = threadIdx.x;
    const int wv = tid >> 6, ln = tid & 63;

    const int srow = wv * 8 + (ln >> 3);
    const int scol = ((ln & 7) ^ ((ln >> 3) & 7)) * 16;
    const u8* Asrc = A + (size_t)(bm + srow) * sA + scol;
    const u8* Bsrc = Bt + (size_t)(bn + srow) * sB + scol;
    char* stA = lds + wv * 1024;
    char* stB = lds + 32768 + wv * 1024;

#define STG_A(P, KT, J)                                                       \
    gload_lds16(Asrc + ((size_t)(KT) << 7) + (size_t)(J) * 64 * sA,           \
                stA + (P) * 65536 + (J) * 8192)
#define STG_B(P, KT, J)                                                       \
    gload_lds16(Bsrc + ((size_t)(KT) << 7) + (size_t)(J) * 64 * sB,           \
                stB + (P) * 65536 + (J) * 8192)
#define STAGE_MID(P, KT)                                                      \
    { STG_B(P, KT, 0); STG_B(P, KT, 1); STG_B(P, KT, 2); STG_B(P, KT, 3);     \
      STG_A(P, KT, 0); STG_A(P, KT, 2); }
#define STAGE_END(P, KT)                                                      \
    { STG_A(P, KT, 1); STG_A(P, KT, 3); }

    const int wr = wv >> 2, wc = wv & 3;
    const int fr = ln & 15, q = ln >> 4;
    const int sw8 = fr & 7;
    const int cbLo = ((2 * q) ^ sw8) << 4;
    const int cbHi = ((2 * q + 1) ^ sw8) << 4;
    const char* Afrag = lds + (size_t)(wr * 128 + fr) * 128;
    const char* Bfrag = lds + 32768 + (size_t)(wc * 64 + fr) * 128;

    v4f acc[8][4];
    #pragma unroll
    for (int m = 0; m < 8; ++m)
        #pragma unroll
        for (int n = 0; n < 4; ++n) acc[m][n] = (v4f)(0.f);

    v8i aP[4], aQ[4], b[4];

#define LD_A(REG, PP, MH)                                                     \
    {                                                                         \
        const char* Ab_ = Afrag + (PP) * 65536;                               \
        _Pragma("unroll")                                                     \
        for (int m = 0; m < 4; ++m) {                                         \
            v4i lo_ = *(const v4i*)(Ab_ + ((MH) * 4 + m) * 2048 + cbLo);      \
            v4i hi_ = *(const v4i*)(Ab_ + ((MH) * 4 + m) * 2048 + cbHi);      \
            v8i f_;                                                           \
            _Pragma("unroll")                                                 \
            for (int z = 0; z < 4; ++z) { f_[z] = lo_[z]; f_[z + 4] = hi_[z]; } \
            REG[m] = f_;                                                      \
        }                                                                     \
    }
#define LD_B(PP)                                                              \
    {                                                                         \
        const char* Bb_ = Bfrag + (PP) * 65536;                               \
        _Pragma("unroll")                                                     \
        for (int n = 0; n < 4; ++n) {                                         \
            v4i lo_ = *(const v4i*)(Bb_ + n * 2048 + cbLo);                   \
            v4i hi_ = *(const v4i*)(Bb_ + n * 2048 + cbHi);                   \
            v8i f_;                                                           \
            _Pragma("unroll")                                                 \
            for (int z = 0; z < 4; ++z) { f_[z] = lo_[z]; f_[z + 4] = hi_[z]; } \
            b[n] = f_;                                                        \
        }                                                                     \
    }
#define MMA(AR, MH)                                                           \
    {                                                                         \
        __builtin_amdgcn_s_setprio(1);                                        \
        _Pragma("unroll")                                                     \
        for (int m = 0; m < 4; ++m)                                           \
            _Pragma("unroll")                                                 \
            for (int n = 0; n < 4; ++n)                                       \
                acc[(MH) * 4 + m][n] =                                        \
                    __builtin_amdgcn_mfma_scale_f32_16x16x128_f8f6f4(         \
                        AR[m], b[n], acc[(MH) * 4 + m][n],                    \
                        0, 0, 0, 0x7F7F7F7F, 0, 0x7F7F7F7F);                  \
        __builtin_amdgcn_s_setprio(0);                                        \
    }

    STAGE_MID(0, t0); STAGE_END(0, t0);
    STAGE_MID(1, t0 + 1); STAGE_END(1, t0 + 1);
    asm volatile("s_waitcnt vmcnt(10)" ::: "memory");
    FENCE; __builtin_amdgcn_s_barrier(); FENCE;
    LD_A(aP, 0, 0);

    int cur = 0;
    for (int t = t0; t < t1 - 2; ++t) {
        asm volatile("s_waitcnt vmcnt(8)" ::: "memory");
        FENCE; __builtin_amdgcn_s_barrier(); FENCE;
        LD_B(cur); LD_A(aQ, cur, 1);
        MMA(aP, 0);
        FENCE; __builtin_amdgcn_s_barrier(); FENCE;
        STAGE_MID(cur, t + 2);
        asm volatile("s_waitcnt vmcnt(8)" ::: "memory");
        MMA(aQ, 1);
        FENCE; __builtin_amdgcn_s_barrier(); FENCE;
        LD_A(aP, cur ^ 1, 0);
        STAGE_END(cur, t + 2);
        cur ^= 1;
    }
    asm volatile("s_waitcnt vmcnt(8)" ::: "memory");
    FENCE; __builtin_amdgcn_s_barrier(); FENCE;
    LD_B(cur); LD_A(aQ, cur, 1);
    MMA(aP, 0);
    MMA(aQ, 1);
    cur ^= 1;
    asm volatile("s_waitcnt vmcnt(0)" ::: "memory");
    FENCE; __builtin_amdgcn_s_barrier(); FENCE;
    LD_B(cur); LD_A(aP, cur, 0); LD_A(aQ, cur, 1);
    MMA(aP, 0);
    MMA(aQ, 1);
#undef MMA
#undef LD_A
#undef LD_B
#undef STAGE_MID
#undef STAGE_END
#undef STG_A
#undef STG_B

    const int rb = q * 4;
    #pragma unroll
    for (int m = 0; m < 8; ++m) {
        const int row = bm + wr * 128 + m * 16 + rb;
        #pragma unroll
        for (int n = 0; n < 4; ++n) {
            const int col = bn + wc * 64 + n * 16 + fr;
            if (EPI == 3) {
                #pragma unroll
                for (int r = 0; r < 4; ++r)
                    Cf[(size_t)(row + r) * N + col] = acc[m][n][r];
            } else if (col < N) {
                const float bv = bias[col];
                #pragma unroll
                for (int r = 0; r < 4; ++r)
                    Cf[(size_t)(row + r) * N + col] =
                        fmaf(acc[m][n][r], fscale, bv);
            }
        }
    }
}

// ---------------------------------------------------------------------------
// 128x128 bf16 kernel: small GEMMs + fused-argmin VQ.
// EPI: 0 = +bias, 1 = tanh(+bias), 2 = VQ argmin. WB/WF: bf16/f32 writes.
// ---------------------------------------------------------------------------
template<int EPI, int WB, int WF>
__global__ __launch_bounds__(256, 2) void mfma_gemm(
    const u16* __restrict__ A, const u16* __restrict__ Bt,
    const float* __restrict__ bias, float* __restrict__ Cf,
    u16* __restrict__ Cb, u64* __restrict__ packed, int M, int N, int K)
{
    __shared__ u16 As[128 * 32];
    __shared__ u16 Bs[128 * 32];
    const int tid = threadIdx.x;
    const int wv = tid >> 6;
    const int ln = tid & 63;
    const int bm = blockIdx.y * 128;
    const int bn = blockIdx.x * 128;

    const int srow = wv * 32 + (ln >> 2);
    const int skel = (ln & 3) * 8;
    const u16* Ap0 = A + (size_t)(bm + srow) * K + skel;
    const u16* Ap1 = Ap0 + (size_t)16 * K;
    const u16* Bp0 = Bt + (size_t)(bn + srow) * K + skel;
    const u16* Bp1 = Bp0 + (size_t)16 * K;
    u16* lA0 = As + wv * 1024;
    u16* lA1 = lA0 + 512;
    u16* lB0 = Bs + wv * 1024;
    u16* lB1 = lB0 + 512;

    const int wr = wv >> 1, wc = wv & 1;
    const int fr = ln & 15;
    const int kg = (ln >> 4) * 8;
    const u16* Afp = As + (wr * 64 + fr) * 32 + kg;
    const u16* Bfp = Bs + (wc * 64 + fr) * 32 + kg;

    v4f acc[4][4];
    #pragma unroll
    for (int m = 0; m < 4; ++m)
        #pragma unroll
        for (int n = 0; n < 4; ++n) acc[m][n] = (v4f)(0.f);

    for (int k0 = 0; k0 < K; k0 += 32) {
        __syncthreads();
        gload_lds16(Ap0 + k0, lA0);
        gload_lds16(Ap1 + k0, lA1);
        gload_lds16(Bp0 + k0, lB0);
        gload_lds16(Bp1 + k0, lB1);
        __syncthreads();
        v8s a[4], b[4];
        #pragma unroll
        for (int m = 0; m < 4; ++m) a[m] = *(const v8s*)(Afp + m * 512);
        #pragma unroll
        for (int n = 0; n < 4; ++n) b[n] = *(const v8s*)(Bfp + n * 512);
        #pragma unroll
        for (int m = 0; m < 4; ++m)
            #pragma unroll
            for (int n = 0; n < 4; ++n)
                acc[m][n] = __builtin_amdgcn_mfma_f32_16x16x32_bf16(
                    a[m], b[n], acc[m][n], 0, 0, 0);
    }

    const int rb = (ln >> 4) * 4;

    if constexpr (EPI == 2) {
        __shared__ u64 smin[128];
        if (tid < 128) smin[tid] = ~0ull;
        __syncthreads();
        #pragma unroll
        for (int m = 0; m < 4; ++m) {
            #pragma unroll
            for (int r = 0; r < 4; ++r) {
                u64 best = ~0ull;
                #pragma unroll
                for (int n = 0; n < 4; ++n) {
                    const int col = bn + wc * 64 + n * 16 + fr;
                    const float s = fmaf(-2.f, acc[m][n][r], bias[col]);
                    const u64 pv =
                        ((u64)float_orderable(s) << 32) | (unsigned)col;
                    best = pv < best ? pv : best;
                }
                #pragma unroll
                for (int msk = 1; msk <= 8; msk <<= 1) {
                    const u64 o = __shfl_xor(best, msk);
                    best = o < best ? o : best;
                }
                if (fr == 0) atomicMin(&smin[wr * 64 + m * 16 + rb + r], best);
            }
        }
        __syncthreads();
        if (tid < 128) atomicMin(&packed[bm + tid], smin[tid]);
    } else {
        #pragma unroll
        for (int m = 0; m < 4; ++m) {
            const int row = bm + wr * 64 + m * 16 + rb;
            #pragma unroll
            for (int n = 0; n < 4; ++n) {
                const int col = bn + wc * 64 + n * 16 + fr;
                if (col < N) {
                    const float bv = bias[col];
                    #pragma unroll
                    for (int r = 0; r < 4; ++r) {
                        float v = acc[m][n][r] + bv;
                        if (EPI == 1) v = tanhf(v);
                        if (WF) Cf[(size_t)(row + r) * N + col] = v;
                        if (WB) Cb[(size_t)(row + r) * N + col] = f2b(v);
                    }
                }
            }
        }
    }
}

// out[i] = bf16(tanh((sum_c P_c) * fs + bias)), 8 elems/thread, NC chunks.
template<int NC>
__global__ __launch_bounds__(256) void reduce_tanh(
    const float* __restrict__ P, const float* __restrict__ bias,
    u16* __restrict__ out, long n8, int N, size_t cs, float fs)
{
    const long stride = (long)gridDim.x * 256;
    for (long i = (long)blockIdx.x * 256 + threadIdx.x; i < n8; i += stride) {
        const size_t e0 = (size_t)i * 8;
        const int col = (int)(e0 & (size_t)(N - 1));
        float4 s0 = *(const float4*)(P + e0);
        float4 s1 = *(const float4*)(P + e0 + 4);
        #pragma unroll
        for (int c = 1; c < NC; ++c) {
            const float4 a = *(const float4*)(P + c * cs + e0);
            const float4 b = *(const float4*)(P + c * cs + e0 + 4);
            s0.x += a.x; s0.y += a.y; s0.z += a.z; s0.w += a.w;
            s1.x += b.x; s1.y += b.y; s1.z += b.z; s1.w += b.w;
        }
        const float4 bv0 = *(const float4*)(bias + col);
        const float4 bv1 = *(const float4*)(bias + col + 4);
        v8s o;
        o[0] = (short)f2b(tanhf(fmaf(s0.x, fs, bv0.x)));
        o[1] = (short)f2b(tanhf(fmaf(s0.y, fs, bv0.y)));
        o[2] = (short)f2b(tanhf(fmaf(s0.z, fs, bv0.z)));
        o[3] = (short)f2b(tanhf(fmaf(s0.w, fs, bv0.w)));
        o[4] = (short)f2b(tanhf(fmaf(s1.x, fs, bv1.x)));
        o[5] = (short)f2b(tanhf(fmaf(s1.y, fs, bv1.y)));
        o[6] = (short)f2b(tanhf(fmaf(s1.z, fs, bv1.z)));
        o[7] = (short)f2b(tanhf(fmaf(s1.w, fs, bv1.w)));
        *(v8s*)(out + e0) = o;
    }
}

// x [4096][20000] f32 -> xb [4096][20096] e4m3, zero-padded. 1 block per row.
__global__ __launch_bounds__(256) void conv_pad_x_f8(
    const float* __restrict__ in, u8* __restrict__ out)
{
    const int row = blockIdx.x;
    const float* src = in + (size_t)row * 20000;
    u8* dst = out + (size_t)row * 20096;
    for (int j = threadIdx.x; j < 2512; j += 256) {
        u64 o = 0;
        if (j < 2500) {
            const float4 a = *(const float4*)(src + j * 8);
            const float4 b = *(const float4*)(src + j * 8 + 4);
            o |= (u64)f2e4m3(a.x) << 0;  o |= (u64)f2e4m3(a.y) << 8;
            o |= (u64)f2e4m3(a.z) << 16; o |= (u64)f2e4m3(a.w) << 24;
            o |= (u64)f2e4m3(b.x) << 32; o |= (u64)f2e4m3(b.y) << 40;
            o |= (u64)f2e4m3(b.z) << 48; o |= (u64)f2e4m3(b.w) << 56;
        }
        *(u64*)(dst + j * 8) = o;
    }
}

// f32 -> bf16 elementwise, 8/thread. n8 = n/8.
__global__ __launch_bounds__(256) void conv_bf16(
    const float* __restrict__ in, u16* __restrict__ out, long n8)
{
    const long stride = (long)gridDim.x * 256;
    for (long i = (long)blockIdx.x * 256 + threadIdx.x; i < n8; i += stride) {
        const float4 a = ((const float4*)in)[i * 2];
        const float4 b = ((const float4*)in)[i * 2 + 1];
        v8s o;
        o[0] = (short)f2b(a.x); o[1] = (short)f2b(a.y);
        o[2] = (short)f2b(a.z); o[3] = (short)f2b(a.w);
        o[4] = (short)f2b(b.x); o[5] = (short)f2b(b.y);
        o[6] = (short)f2b(b.z); o[7] = (short)f2b(b.w);
        *(v8s*)(out + i * 8) = o;
    }
}

// W[K][N] f32 -> Wt[N][Kp] bf16, rows k>=K zero-filled. block (32,8).
__global__ __launch_bounds__(256) void trans_bf16p(
    const float* __restrict__ W, u16* __restrict__ Wt, int K, int N, int Kp)
{
    __shared__ float t[32][33];
    const int tx = threadIdx.x, ty = threadIdx.y;
    const int n0 = blockIdx.x * 32, k0 = blockIdx.y * 32;
    #pragma unroll
    for (int i = 0; i < 32; i += 8) {
        const int n = n0 + tx;
        const int k = k0 + ty + i;
        t[ty + i][tx] = (n < N && k < K) ? W[(size_t)k * N + n] : 0.f;
    }
    __syncthreads();
    #pragma unroll
    for (int i = 0; i < 32; i += 8) {
        const int n = n0 + ty + i;
        if (n < N) Wt[(size_t)n * Kp + k0 + tx] = f2b(t[tx][ty + i]);
    }
}

// W[K][N] f32 -> Wt[N][Kp] e4m3 of (w*scale), rows k>=K zero-filled.
__global__ __launch_bounds__(256) void trans_f8p(
    const float* __restrict__ W, u8* __restrict__ Wt, int K, int N, int Kp,
    float scale)
{
    __shared__ float t[32][33];
    const int tx = threadIdx.x, ty = threadIdx.y;
    const int n0 = blockIdx.x * 32, k0 = blockIdx.y * 32;
    #pragma unroll
    for (int i = 0; i < 32; i += 8) {
        const int n = n0 + tx;
        const int k = k0 + ty + i;
        t[ty + i][tx] = (n < N && k < K) ? W[(size_t)k * N + n] * scale : 0.f;
    }
    __syncthreads();
    #pragma unroll
    for (int i = 0; i < 32; i += 8) {
        const int n = n0 + ty + i;
        if (n < N) Wt[(size_t)n * Kp + k0 + tx] = f2e4m3(t[tx][ty + i]);
    }
}

// cnorm[k] = ||codebook[k]||^2 (f32), one wave per row.
__global__ __launch_bounds__(64) void cnorm_k(
    const float* __restrict__ CB, float* __restrict__ cn)
{
    const float* row = CB + (size_t)blockIdx.x * 512;
    float s = 0.f;
    #pragma unroll
    for (int u = 0; u < 8; ++u) {
        const float v = row[threadIdx.x + 64 * u];
        s = fmaf(v, v, s);
    }
    #pragma unroll
    for (int m = 32; m; m >>= 1) s += __shfl_down(s, m);
    if (threadIdx.x == 0) cn[blockIdx.x] = s;
}

__global__ void init_packed(u64* __restrict__ p)
{
    p[blockIdx.x * 256 + threadIdx.x] = ~0ull;
}

// gather q rows -> qout (f32) + qb (bf16); block partials of sum((q-z)^2).
__global__ __launch_bounds__(256) void quant_loss(
    const u64* __restrict__ packed, const float* __restrict__ CB,
    const float* __restrict__ Z, float* __restrict__ qout,
    u16* __restrict__ qb, double* __restrict__ partials)
{
    const int gid = blockIdx.x * 256 + threadIdx.x;
    const int i = gid >> 7;
    const int j = (gid & 127) << 2;
    const int k = (int)(packed[i] & 0xffffffffull);
    const float4 c = *(const float4*)(CB + (size_t)k * 512 + j);
    const float4 z = *(const float4*)(Z + (size_t)i * 512 + j);
    const size_t o = (size_t)i * 512 + j;
    qout[o + 0] = c.x; qout[o + 1] = c.y; qout[o + 2] = c.z; qout[o + 3] = c.w;
    qb[o + 0] = f2b(c.x); qb[o + 1] = f2b(c.y);
    qb[o + 2] = f2b(c.z); qb[o + 3] = f2b(c.w);
    const float d0 = c.x - z.x, d1 = c.y - z.y, d2 = c.z - z.z, d3 = c.w - z.w;
    float local = d0 * d0 + d1 * d1 + d2 * d2 + d3 * d3;
    #pragma unroll
    for (int m = 32; m; m >>= 1) local += __shfl_down(local, m);
    __shared__ float wsum[4];
    if ((threadIdx.x & 63) == 0) wsum[threadIdx.x >> 6] = local;
    __syncthreads();
    if (threadIdx.x == 0)
        partials[blockIdx.x] = (double)wsum[0] + (double)wsum[1] +
                               (double)wsum[2] + (double)wsum[3];
}

__global__ __launch_bounds__(256) void loss_final(
    const double* __restrict__ partials, float* __restrict__ out)
{
    double s = 0.0;
    for (int u = threadIdx.x; u < 2048; u += 256) s += partials[u];
    #pragma unroll
    for (int m = 32; m; m >>= 1) s += __shfl_down(s, m);
    __shared__ double ws[4];
    if ((threadIdx.x & 63) == 0) ws[threadIdx.x >> 6] = s;
    __syncthreads();
    if (threadIdx.x == 0)
        out[0] = (float)(1.25 * (ws[0] + ws[1] + ws[2] + ws[3]) / 2097152.0);
}

extern "C" void kernel_launch(void* const* d_in, const int* in_sizes, int n_in,
                              void* d_out, int out_size, void* d_ws, size_t ws_size,
                              hipStream_t stream)
{
    const float* x  = (const float*)d_in[0];
    const float* W1 = (const float*)d_in[1];
    const float* b1 = (const float*)d_in[2];
    const float* W2 = (const float*)d_in[3];
    const float* b2 = (const float*)d_in[4];
    const float* W3 = (const float*)d_in[5];
    const float* b3 = (const float*)d_in[6];
    const float* CB = (const float*)d_in[7];
    const float* W4 = (const float*)d_in[8];
    const float* b4 = (const float*)d_in[9];
    const float* W5 = (const float*)d_in[10];
    const float* b5 = (const float*)d_in[11];
    const float* W6 = (const float*)d_in[12];
    const float* b6 = (const float*)d_in[13];

    float* out  = (float*)d_out;
    float* xrec = out + 1;
    float* qout = out + 1 + (size_t)4096 * 20000;

    // scratch inside d_out's x_recon region (dead until final GEMM):
    u8*    XB8   = (u8*)((char*)d_out + 16);                 // [4096][20096] e4m3
    float* PART1 = (float*)((char*)d_out + 16 + 82313216);   // 2x[4096][2048] f32

    char* ws = (char*)d_ws;
    u8*  W1T8 = (u8*)(ws + 0);            // [2048][20096] e4m3 (dead after GEMM1)
    u16* WT6  = (u16*)(ws + 0);           // [20224][2048] bf16 (after GEMM1)
    u16* WT2  = (u16*)(ws + 82837504);    // [1024][2048] bf16
    u16* WT3  = (u16*)(ws + 87031808);    // [512][1024]
    u16* CBB  = (u16*)(ws + 88080384);    // [8192][512]
    u16* WT4  = (u16*)(ws + 96468992);    // [1024][512]
    u16* WT5  = (u16*)(ws + 97517568);    // [2048][1024]
    u16* ACT1 = (u16*)(ws + 101711872);   // [4096][2048] z1, later h2
    u16* ACT2 = (u16*)(ws + 118489088);   // [4096][1024] z2, later h1
    float* Z3F = (float*)(ws + 126877696); // [4096][512]
    u16* Z3B  = (u16*)(ws + 135266304);   // [4096][512]
    u16* QB   = (u16*)(ws + 139460608);   // [4096][512]
    float* CN = (float*)(ws + 143654912);
    u64* PACKED = (u64*)(ws + 143687680);
    double* PART = (double*)(ws + 143720448);

    const dim3 blk(256);

    // ---- precompute ----
    conv_pad_x_f8<<<dim3(4096), blk, 0, stream>>>(x, XB8);
    conv_bf16<<<dim3(2048), blk, 0, stream>>>(CB, CBB, 524288L);
    trans_f8p<<<dim3(64, 628), dim3(32, 8), 0, stream>>>(
        W1, W1T8, 20000, 2048, 20096, 4096.f);          // W1 x 2^12
    trans_bf16p<<<dim3(32, 64),  dim3(32, 8), 0, stream>>>(W2, WT2, 2048, 1024, 2048);
    trans_bf16p<<<dim3(16, 32),  dim3(32, 8), 0, stream>>>(W3, WT3, 1024, 512, 1024);
    trans_bf16p<<<dim3(32, 16),  dim3(32, 8), 0, stream>>>(W4, WT4, 512, 1024, 512);
    trans_bf16p<<<dim3(64, 32),  dim3(32, 8), 0, stream>>>(W5, WT5, 1024, 2048, 1024);
    cnorm_k<<<dim3(8192), dim3(64), 0, stream>>>(CB, CN);
    init_packed<<<dim3(16), blk, 0, stream>>>(PACKED);

    // ---- encoder ----
    // GEMM1: fp8 256^2, split-K 2 (256 blocks); 2^-12 compensation in reduce
    gemm256f8<3><<<dim3(8, 16, 2), dim3(512), 131072, stream>>>(
        XB8, W1T8, nullptr, PART1, 1.f, 4096, 2048, 20096, 20096, 20096);
    reduce_tanh<2><<<dim3(4096), blk, 0, stream>>>(
        PART1, b1, ACT1, 1048576L, 2048, (size_t)4096 * 2048, 1.f / 4096.f);
    // W1T8 dead; transpose W6 (bf16) into the same arena
    trans_bf16p<<<dim3(625, 64), dim3(32, 8), 0, stream>>>(W6, WT6, 2048, 20000, 2048);
    mfma_gemm<1, 1, 0><<<dim3(8, 32), blk, 0, stream>>>(
        ACT1, WT2, b2, nullptr, ACT2, nullptr, 4096, 1024, 2048);
    mfma_gemm<1, 1, 1><<<dim3(4, 32), blk, 0, stream>>>(
        ACT2, WT3, b3, Z3F, Z3B, nullptr, 4096, 512, 1024);

    // ---- VQ: 128^2 score GEMM with fused argmin, then gather + loss ----
    mfma_gemm<2, 0, 0><<<dim3(64, 32), blk, 0, stream>>>(
        Z3B, CBB, CN, nullptr, nullptr, PACKED, 4096, 8192, 512);
    quant_loss<<<dim3(2048), blk, 0, stream>>>(PACKED, CB, Z3F, qout, QB, PART);
    loss_final<<<dim3(1), blk, 0, stream>>>(PART, out);

    // ---- decoder ----
    mfma_gemm<1, 1, 0><<<dim3(8, 32), blk, 0, stream>>>(
        QB, WT4, b4, nullptr, ACT2, nullptr, 4096, 1024, 512);
    mfma_gemm<1, 1, 0><<<dim3(16, 32), blk, 0, stream>>>(
        ACT2, WT5, b5, nullptr, ACT1, nullptr, 4096, 2048, 1024);
    // GEMM6: bf16 256^2, grid padded to 80x16 (bx=79 dead) for supertile map
    gemm256<0><<<dim3(80, 16), dim3(512), 131072, stream>>>(
        ACT1, WT6, b6, xrec, 4096, 20000, 2048, 2048, 2048);
}